// Round 5
// baseline (560.449 us; speedup 1.0000x reference)
//
#include <hip/hip_runtime.h>
#include <math.h>

#define NN 50000
#define NE 800000
#define NFD 256
#define HD 64
#define QDD 128
#define TDD 32
#define NTT 64
#define NLAY 3
#define LCLAMP 6.1030340f   // atanh(1 - 1e-5)
#define CHUNK 1024
#define NCHUNK 49           // ceil(50000/1024)

typedef unsigned int uint;
typedef unsigned short ushort;

__device__ __forceinline__ ushort f2bf(float f) {
  uint u = __float_as_uint(f);
  uint r = (u + 0x7FFFu + ((u >> 16) & 1u)) >> 16;
  return (ushort)r;
}
__device__ __forceinline__ float bflo(uint w) { return __uint_as_float(w << 16); }
__device__ __forceinline__ float bfhi(uint w) { return __uint_as_float(w & 0xFFFF0000u); }

__device__ __forceinline__ float bfly_sum(float v) {
  v += __shfl_xor(v, 1, 64);
  v += __shfl_xor(v, 2, 64);
  v += __shfl_xor(v, 4, 64);
  v += __shfl_xor(v, 8, 64);
  v += __shfl_xor(v, 16, 64);
  v += __shfl_xor(v, 32, 64);
  return v;
}

// ---------------------------------------------------------------- setup (small dense precomputes)
__global__ void k_setup(const float* __restrict__ edge_desc, const float* __restrict__ query,
                        const float* __restrict__ Wq, const float* __restrict__ bq,
                        const float* __restrict__ Ws, const float* __restrict__ bs,
                        const float* __restrict__ attn_a,
                        const float* __restrict__ Wns1, const float* __restrict__ bns1,
                        const float* __restrict__ Wes1, const float* __restrict__ bes1,
                        float* __restrict__ out_type_emb,
                        float* __restrict__ qb, float* __restrict__ ta3,
                        float* __restrict__ Te2) {
  __shared__ float te_l[NTT * TDD];
  __shared__ float q_l[HD];
  __shared__ float qe_l[HD];
  int t = threadIdx.x;
  if (t < HD) {
    float acc = bq[t];
    for (int k = 0; k < QDD; ++k) acc += query[k] * Wq[k * HD + t];
    q_l[t] = acc;
  }
  for (int idx = t; idx < NTT * TDD; idx += 256) {
    int ty = idx / TDD, d = idx % TDD;
    float acc = bs[d];
    for (int k = 0; k < 64; ++k) acc += edge_desc[ty * 64 + k] * Ws[k * TDD + d];
    float v = tanhf(acc);
    te_l[idx] = v;
    out_type_emb[idx] = v;
  }
  __syncthreads();
  if (t < NLAY * NTT) {
    int l = t / NTT, ty = t % NTT;
    float acc = 0.f;
    for (int d = 0; d < TDD; ++d) acc += te_l[ty * TDD + d] * attn_a[l * (2 * HD + TDD) + 2 * HD + d];
    ta3[t] = acc;
  }
  if (t < HD) {
    float a1 = bns1[t], a2 = bes1[t];
    for (int k = 0; k < HD; ++k) {
      a1 += q_l[k] * Wns1[(HD + k) * HD + t];
      a2 += q_l[k] * Wes1[(2 * HD + TDD + k) * HD + t];
    }
    qb[t] = a1;
    qe_l[t] = a2;
  }
  __syncthreads();
  for (int idx = t; idx < NTT * HD; idx += 256) {
    int ty = idx >> 6, j = idx & 63;
    float acc = qe_l[j];
    for (int d = 0; d < TDD; ++d) acc += te_l[ty * TDD + d] * Wes1[(2 * HD + d) * HD + j];
    Te2[idx] = acc;
  }
}

// ---------------------------------------------------------------- CSR build
__global__ void k_hist(const int* __restrict__ dst, int* __restrict__ cnt) {
  int e = blockIdx.x * 256 + threadIdx.x;
  if (e < NE) atomicAdd(&cnt[dst[e]], 1);
}

__global__ void k_scanA(const int* __restrict__ cnt, int* __restrict__ bsum) {
  __shared__ int ws[4];
  int t = threadIdx.x;
  int c0 = blockIdx.x * CHUNK;
  int s = 0;
#pragma unroll
  for (int it = 0; it < 4; ++it) {
    int i = c0 + it * 256 + t;
    if (i < NN) s += cnt[i];
  }
#pragma unroll
  for (int off = 1; off < 64; off <<= 1) s += __shfl_xor(s, off, 64);
  if ((t & 63) == 0) ws[t >> 6] = s;
  __syncthreads();
  if (t == 0) bsum[blockIdx.x] = ws[0] + ws[1] + ws[2] + ws[3];
}

__global__ void k_scanB(const int* __restrict__ bsum, int* __restrict__ boff,
                        int* __restrict__ row_ptr) {
  int t = threadIdx.x;  // 64 threads
  int v = (t < NCHUNK) ? bsum[t] : 0;
  int x = v;
#pragma unroll
  for (int off = 1; off < 64; off <<= 1) {
    int y = __shfl_up(x, off, 64);
    if (t >= off) x += y;
  }
  if (t < NCHUNK) boff[t] = x - v;
  if (t == 63) row_ptr[NN] = x;
}

__global__ void k_scanC(const int* __restrict__ cnt, const int* __restrict__ boff,
                        int* __restrict__ row_ptr, int* __restrict__ cursor) {
  __shared__ int wsum[4], woff_s[4];
  int t = threadIdx.x;
  int c0 = blockIdx.x * CHUNK;
  int i0 = c0 + t * 4;
  int v0 = (i0 + 0 < NN) ? cnt[i0 + 0] : 0;
  int v1 = (i0 + 1 < NN) ? cnt[i0 + 1] : 0;
  int v2 = (i0 + 2 < NN) ? cnt[i0 + 2] : 0;
  int v3 = (i0 + 3 < NN) ? cnt[i0 + 3] : 0;
  int s4 = v0 + v1 + v2 + v3;
  int lane = t & 63, wid = t >> 6;
  int x = s4;
#pragma unroll
  for (int off = 1; off < 64; off <<= 1) {
    int y = __shfl_up(x, off, 64);
    if (lane >= off) x += y;
  }
  if (lane == 63) wsum[wid] = x;
  __syncthreads();
  if (t == 0) {
    int a = 0;
    for (int i = 0; i < 4; ++i) { woff_s[i] = a; a += wsum[i]; }
  }
  __syncthreads();
  int base = boff[blockIdx.x] + woff_s[wid] + (x - s4);
  int r0 = base, r1 = base + v0, r2 = r1 + v1, r3 = r2 + v2;
  if (i0 + 0 < NN) { row_ptr[i0 + 0] = r0; cursor[i0 + 0] = r0; }
  if (i0 + 1 < NN) { row_ptr[i0 + 1] = r1; cursor[i0 + 1] = r1; }
  if (i0 + 2 < NN) { row_ptr[i0 + 2] = r2; cursor[i0 + 2] = r2; }
  if (i0 + 3 < NN) { row_ptr[i0 + 3] = r3; cursor[i0 + 3] = r3; }
}

__global__ void k_scatter(const int* __restrict__ src, const int* __restrict__ dst,
                          const int* __restrict__ etype, int* __restrict__ cursor,
                          uint* __restrict__ csr) {
  int e = blockIdx.x * 256 + threadIdx.x;
  if (e < NE) {
    int d = dst[e];
    int pos = atomicAdd(&cursor[d], 1);
    csr[pos] = (uint)src[e] | ((uint)etype[e] << 16);
  }
}

// ---------------------------------------------------------------- initial projection
// ht0 = clamp_norm((X @ Wn + bn) * ts).  lane = output col j; weights RESIDENT in VGPR
// (__launch_bounds__(256,4) -> 128-VGPR budget so wcol[64] is not rematerialized);
// activations stream through SGPRs (wave-uniform row addresses). 4 waves split K=256.
__global__ void __launch_bounds__(256, 4) k_proj(const float* __restrict__ X,
                                                 const float* __restrict__ Wn,
                                                 const float* __restrict__ bn,
                                                 const float* __restrict__ ts_p,
                                                 float* __restrict__ ht0) {
  __shared__ float ps[16][4][64];  // 16 KB partials
  int t = threadIdx.x;
  int lane = t & 63;
  int wv = t >> 6;
  int n0 = blockIdx.x * 64;
  float wcol[64];
#pragma unroll
  for (int k = 0; k < 64; ++k) wcol[k] = Wn[(wv * 64 + k) * HD + lane];
  float vbn = bn[lane];
  float ts = ts_p[0];

  for (int batch = 0; batch < 4; ++batch) {
    int b0 = n0 + batch * 16;
#pragma unroll 4
    for (int i = 0; i < 16; ++i) {
      int m = b0 + i;
      if (m < NN) {
        const float* ar = X + (size_t)__builtin_amdgcn_readfirstlane(m * NFD + wv * 64);
        float acc = 0.f;
#pragma unroll
        for (int k = 0; k < 64; ++k) acc = fmaf(ar[k], wcol[k], acc);
        ps[i][wv][lane] = acc;
      }
    }
    __syncthreads();
#pragma unroll
    for (int ii = 0; ii < 4; ++ii) {
      int i = wv * 4 + ii;
      int m = b0 + i;
      if (m < NN) {
        float v = ps[i][0][lane] + ps[i][1][lane] + ps[i][2][lane] + ps[i][3][lane];
        v = (v + vbn) * ts;
        float ssq = bfly_sum(v * v);
        float nu = fmaxf(sqrtf(ssq), 1e-15f);
        float sc = fminf(nu, LCLAMP) / nu;
        ht0[(size_t)m * HD + lane] = v * sc;
      }
    }
    __syncthreads();
  }
}

// ---------------------------------------------------------------- msg = ht @ Wmp + bmp (bf16); p_src/p_dst
// lane = output col; weights resident in VGPR; each wave streams 16 nodes.
__global__ void __launch_bounds__(256, 4) k_msg(const float* __restrict__ ht,
                                                const float* __restrict__ Wmp_l,
                                                const float* __restrict__ bmp_l,
                                                const float* __restrict__ attn_l,
                                                ushort* __restrict__ msgbf,
                                                float* __restrict__ p_src,
                                                float* __restrict__ p_dst) {
  int t = threadIdx.x;
  int lane = t & 63;
  int wv = t >> 6;
  int n0 = blockIdx.x * 64 + wv * 16;
  float wcol[64];
#pragma unroll
  for (int k = 0; k < 64; ++k) wcol[k] = Wmp_l[k * HD + lane];
  float vb = bmp_l[lane];
  float va1 = attn_l[lane];
  float va2 = attn_l[HD + lane];

#pragma unroll 4
  for (int i = 0; i < 16; ++i) {
    int m = n0 + i;
    if (m >= NN) break;
    int mu = __builtin_amdgcn_readfirstlane(m);
    const float* ar = ht + (size_t)mu * HD;
    float va = ar[lane];          // coalesced vector row copy (for the reduces)
    float acc = vb;
#pragma unroll
    for (int k = 0; k < 64; ++k) acc = fmaf(ar[k], wcol[k], acc);
    float r1 = bfly_sum(va * va1);
    float r2 = bfly_sum(va * va2);
    if (lane == 0) { p_src[mu] = r1; p_dst[mu] = r2; }
    msgbf[(size_t)mu * HD + lane] = f2bf(acc);
  }
}

// ---------------------------------------------------------------- softmax-aggregate (wave/node, 8-wide gather)
__global__ void __launch_bounds__(256) k_agg(const int* __restrict__ row_ptr,
                                             const uint* __restrict__ csr,
                                             const float* __restrict__ p_src,
                                             const float* __restrict__ p_dst,
                                             const float* __restrict__ ta_l,
                                             const ushort* __restrict__ msgbf,
                                             float* __restrict__ ht_out,
                                             float* __restrict__ s_buf) {
  int lane = threadIdx.x & 63;
  int n = (blockIdx.x * 256 + threadIdx.x) >> 6;
  if (n >= NN) return;
  int start = row_ptr[n], end = row_ptr[n + 1];
  int deg = end - start;
  float pd = p_dst[n];
  int lq = lane & 7, lg = lane >> 3;
  float acc[8];
#pragma unroll
  for (int u = 0; u < 8; ++u) acc[u] = 0.f;
  float exsum = 0.f;

  if (deg <= 64) {
    bool valid = lane < deg;
    float s = -3.4e38f;
    int sidx = 0;
    if (valid) {
      uint pk = csr[start + lane];
      sidx = (int)(pk & 0xFFFFu);
      int ty = (int)(pk >> 16);
      float v = p_src[sidx] + pd + ta_l[ty];
      s = (v > 0.f) ? v : 0.2f * v;
    }
    float m = s;
#pragma unroll
    for (int off = 32; off >= 1; off >>= 1) m = fmaxf(m, __shfl_xor(m, off, 64));
    float ex = valid ? __expf(s - m) : 0.f;
    exsum = ex;
    for (int it = 0; it < deg; it += 8) {
      int el = it + lg;
      float exk = __shfl(ex, el, 64);
      int sk = __shfl(sidx, el, 64);
      if (el < deg) {
        uint4 mv = *(const uint4*)&msgbf[(size_t)sk * HD + lq * 8];
        acc[0] += exk * bflo(mv.x); acc[1] += exk * bfhi(mv.x);
        acc[2] += exk * bflo(mv.y); acc[3] += exk * bfhi(mv.y);
        acc[4] += exk * bflo(mv.z); acc[5] += exk * bfhi(mv.z);
        acc[6] += exk * bflo(mv.w); acc[7] += exk * bfhi(mv.w);
      }
    }
  } else {
    float m = -3.4e38f;
    for (int base = start; base < end; base += 64) {
      int i = base + lane;
      float s = -3.4e38f;
      if (i < end) {
        uint pk = csr[i];
        int sidx = (int)(pk & 0xFFFFu);
        int ty = (int)(pk >> 16);
        float v = p_src[sidx] + pd + ta_l[ty];
        s = (v > 0.f) ? v : 0.2f * v;
        s_buf[i] = s;
      }
      m = fmaxf(m, s);
    }
#pragma unroll
    for (int off = 32; off >= 1; off >>= 1) m = fmaxf(m, __shfl_xor(m, off, 64));
    for (int base = start; base < end; base += 64) {
      int i = base + lane;
      if (i < end) {
        float ex = __expf(s_buf[i] - m);
        s_buf[i] = ex;
        exsum += ex;
      }
    }
    for (int it = start; it < end; it += 8) {
      int el = it + lg;
      if (el < end) {
        float exk = s_buf[el];
        int sk = (int)(csr[el] & 0xFFFFu);
        uint4 mv = *(const uint4*)&msgbf[(size_t)sk * HD + lq * 8];
        acc[0] += exk * bflo(mv.x); acc[1] += exk * bfhi(mv.x);
        acc[2] += exk * bflo(mv.y); acc[3] += exk * bfhi(mv.y);
        acc[4] += exk * bflo(mv.z); acc[5] += exk * bfhi(mv.z);
        acc[6] += exk * bflo(mv.w); acc[7] += exk * bfhi(mv.w);
      }
    }
  }
#pragma unroll
  for (int u = 0; u < 8; ++u) {
    acc[u] += __shfl_xor(acc[u], 8, 64);
    acc[u] += __shfl_xor(acc[u], 16, 64);
    acc[u] += __shfl_xor(acc[u], 32, 64);
  }
#pragma unroll
  for (int off = 32; off >= 1; off >>= 1) exsum += __shfl_xor(exsum, off, 64);
  float inv = 1.f / (exsum + 1e-15f);
  float ss = 0.f;
#pragma unroll
  for (int u = 0; u < 8; ++u) {
    float v = fmaxf(acc[u] * inv, 0.f);
    acc[u] = v;
    ss += v * v;
  }
  ss += __shfl_xor(ss, 1, 64);
  ss += __shfl_xor(ss, 2, 64);
  ss += __shfl_xor(ss, 4, 64);
  float nu = fmaxf(sqrtf(ss), 1e-15f);
  float sc = fminf(nu, LCLAMP) / nu;
  if (lane < 8) {
    *(float4*)&ht_out[(size_t)n * HD + lane * 8] =
        make_float4(acc[0] * sc, acc[1] * sc, acc[2] * sc, acc[3] * sc);
    *(float4*)&ht_out[(size_t)n * HD + lane * 8 + 4] =
        make_float4(acc[4] * sc, acc[5] * sc, acc[6] * sc, acc[7] * sc);
  }
}

// ---------------------------------------------------------------- heads (wave-specialized):
// wv0: node head (Wns1/qb/Wns2 -> node_scores); wv1: Asrc; wv2: Adst; wv3: h_out
__global__ void __launch_bounds__(256, 4) k_score(const float* __restrict__ ht,
                                                  const float* __restrict__ Wns1,
                                                  const float* __restrict__ qb,
                                                  const float* __restrict__ Wns2,
                                                  const float* __restrict__ bns2,
                                                  const float* __restrict__ Wes1,
                                                  float* __restrict__ node_scores,
                                                  float* __restrict__ h_out,
                                                  ushort* __restrict__ Asrc,
                                                  ushort* __restrict__ Adst) {
  int t = threadIdx.x;
  int lane = t & 63;
  int wv = t >> 6;
  int n0 = blockIdx.x * 64;

  if (wv == 0) {
    float wcol[64];
#pragma unroll
    for (int k = 0; k < 64; ++k) wcol[k] = Wns1[k * HD + lane];
    float vqb = qb[lane];
    float vw2 = Wns2[lane];
    float b2 = bns2[0];
#pragma unroll 4
    for (int i = 0; i < 64; ++i) {
      int m = n0 + i;
      if (m >= NN) break;
      int mu = __builtin_amdgcn_readfirstlane(m);
      const float* ar = ht + (size_t)mu * HD;
      float acc = 0.f;
#pragma unroll
      for (int k = 0; k < 64; ++k) acc = fmaf(ar[k], wcol[k], acc);
      float z = fmaxf(acc + vqb, 0.f) * vw2;
      float logit = bfly_sum(z) + b2;
      if (lane == 0) node_scores[mu] = 1.f / (1.f + __expf(-logit));
    }
  } else if (wv == 1) {
    float wcol[64];
#pragma unroll
    for (int k = 0; k < 64; ++k) wcol[k] = Wes1[k * HD + lane];
#pragma unroll 4
    for (int i = 0; i < 64; ++i) {
      int m = n0 + i;
      if (m >= NN) break;
      int mu = __builtin_amdgcn_readfirstlane(m);
      const float* ar = ht + (size_t)mu * HD;
      float acc = 0.f;
#pragma unroll
      for (int k = 0; k < 64; ++k) acc = fmaf(ar[k], wcol[k], acc);
      Asrc[(size_t)mu * HD + lane] = f2bf(acc);
    }
  } else if (wv == 2) {
    float wcol[64];
#pragma unroll
    for (int k = 0; k < 64; ++k) wcol[k] = Wes1[(HD + k) * HD + lane];
#pragma unroll 4
    for (int i = 0; i < 64; ++i) {
      int m = n0 + i;
      if (m >= NN) break;
      int mu = __builtin_amdgcn_readfirstlane(m);
      const float* ar = ht + (size_t)mu * HD;
      float acc = 0.f;
#pragma unroll
      for (int k = 0; k < 64; ++k) acc = fmaf(ar[k], wcol[k], acc);
      Adst[(size_t)mu * HD + lane] = f2bf(acc);
    }
  } else {
#pragma unroll 4
    for (int i = 0; i < 64; ++i) {
      int m = n0 + i;
      if (m >= NN) break;
      int mu = __builtin_amdgcn_readfirstlane(m);
      float va = ht[(size_t)mu * HD + lane];
      float ssq = bfly_sum(va * va);
      float nu = fmaxf(sqrtf(ssq), 1e-15f);
      float hs = tanhf(nu) / nu;
      h_out[(size_t)mu * HD + lane] = va * hs;
    }
  }
}

// ---------------------------------------------------------------- edge scores (8 lanes/edge, 8 edges/wave)
__global__ void __launch_bounds__(256) k_edge(const int* __restrict__ src,
                                              const int* __restrict__ dst,
                                              const int* __restrict__ etype,
                                              const ushort* __restrict__ Asrc,
                                              const ushort* __restrict__ Adst,
                                              const float* __restrict__ Te2,
                                              const float* __restrict__ Wes2,
                                              const float* __restrict__ bes2,
                                              float* __restrict__ edge_scores) {
  int t = threadIdx.x;
  int lane = t & 63;
  int lq = lane & 7, lg = lane >> 3;
  int w = (blockIdx.x * 256 + t) >> 6;
  int e = w * 8 + lg;
  float p = 0.f;
  if (e < NE) {
    int si = src[e], di = dst[e], ti = etype[e];
    uint4 av = *(const uint4*)&Asrc[(size_t)si * HD + lq * 8];
    uint4 bv = *(const uint4*)&Adst[(size_t)di * HD + lq * 8];
    const float* tp = &Te2[ti * HD + lq * 8];
    float4 t0 = *(const float4*)tp;
    float4 t1 = *(const float4*)(tp + 4);
    const float* wp = &Wes2[lq * 8];
    float4 w0 = *(const float4*)wp;
    float4 w1 = *(const float4*)(wp + 4);
    p += fmaxf(bflo(av.x) + bflo(bv.x) + t0.x, 0.f) * w0.x;
    p += fmaxf(bfhi(av.x) + bfhi(bv.x) + t0.y, 0.f) * w0.y;
    p += fmaxf(bflo(av.y) + bflo(bv.y) + t0.z, 0.f) * w0.z;
    p += fmaxf(bfhi(av.y) + bfhi(bv.y) + t0.w, 0.f) * w0.w;
    p += fmaxf(bflo(av.z) + bflo(bv.z) + t1.x, 0.f) * w1.x;
    p += fmaxf(bfhi(av.z) + bfhi(bv.z) + t1.y, 0.f) * w1.y;
    p += fmaxf(bflo(av.w) + bflo(bv.w) + t1.z, 0.f) * w1.z;
    p += fmaxf(bfhi(av.w) + bfhi(bv.w) + t1.w, 0.f) * w1.w;
  }
  p += __shfl_xor(p, 1, 64);
  p += __shfl_xor(p, 2, 64);
  p += __shfl_xor(p, 4, 64);
  if (e < NE && lq == 0) edge_scores[e] = 1.f / (1.f + __expf(-(p + bes2[0])));
}

// ---------------------------------------------------------------- launch
extern "C" void kernel_launch(void* const* d_in, const int* in_sizes, int n_in,
                              void* d_out, int out_size, void* d_ws, size_t ws_size,
                              hipStream_t stream) {
  const float* node_features = (const float*)d_in[0];
  const float* edge_desc = (const float*)d_in[1];
  const float* query = (const float*)d_in[2];
  const float* Wn = (const float*)d_in[3];
  const float* bn = (const float*)d_in[4];
  const float* ts = (const float*)d_in[5];
  const float* Wq = (const float*)d_in[6];
  const float* bq = (const float*)d_in[7];
  const float* Ws_ = (const float*)d_in[8];
  const float* bs = (const float*)d_in[9];
  const float* attn_a = (const float*)d_in[10];
  const float* Wmp = (const float*)d_in[11];
  const float* bmp = (const float*)d_in[12];
  const float* Wns1 = (const float*)d_in[13];
  const float* bns1 = (const float*)d_in[14];
  const float* Wns2 = (const float*)d_in[15];
  const float* bns2 = (const float*)d_in[16];
  const float* Wes1 = (const float*)d_in[17];
  const float* bes1 = (const float*)d_in[18];
  const float* Wes2 = (const float*)d_in[19];
  const float* bes2 = (const float*)d_in[20];
  const int* edge_index = (const int*)d_in[21];
  const int* etype = (const int*)d_in[22];
  const int* src = edge_index;
  const int* dst = edge_index + NE;

  float* out_ns = (float*)d_out;
  float* out_es = out_ns + NN;
  float* out_h = out_es + NE;
  float* out_te = out_h + (size_t)NN * HD;

  char* w = (char*)d_ws;
  auto alloc = [&](size_t bytes) {
    char* p = w;
    w += (bytes + 1023) & ~(size_t)1023;
    return p;
  };
  float* ht_a = (float*)alloc((size_t)NN * HD * 4);
  float* ht_b = (float*)alloc((size_t)NN * HD * 4);
  ushort* msgbf = (ushort*)alloc((size_t)NN * HD * 2);
  ushort* Asrc = (ushort*)alloc((size_t)NN * HD * 2);
  ushort* Adst = (ushort*)alloc((size_t)NN * HD * 2);
  float* p_src = (float*)alloc(NN * 4);
  float* p_dst = (float*)alloc(NN * 4);
  float* s_buf = (float*)alloc(NE * 4);
  float* qb = (float*)alloc(HD * 4);
  float* ta3 = (float*)alloc(NLAY * NTT * 4);
  float* Te2 = (float*)alloc(NTT * HD * 4);
  int* cnt = (int*)alloc(NN * 4);
  int* row_ptr = (int*)alloc((NN + 1) * 4);
  int* cursor = (int*)alloc(NN * 4);
  int* bsum = (int*)alloc(NCHUNK * 4);
  int* boff = (int*)alloc(NCHUNK * 4);
  uint* csr = (uint*)alloc(NE * 4);

  hipMemsetAsync(cnt, 0, NN * 4, stream);
  k_setup<<<1, 256, 0, stream>>>(edge_desc, query, Wq, bq, Ws_, bs, attn_a, Wns1, bns1,
                                 Wes1, bes1, out_te, qb, ta3, Te2);
  k_hist<<<NE / 256, 256, 0, stream>>>(dst, cnt);
  k_scanA<<<NCHUNK, 256, 0, stream>>>(cnt, bsum);
  k_scanB<<<1, 64, 0, stream>>>(bsum, boff, row_ptr);
  k_scanC<<<NCHUNK, 256, 0, stream>>>(cnt, boff, row_ptr, cursor);
  k_scatter<<<NE / 256, 256, 0, stream>>>(src, dst, etype, cursor, csr);
  k_proj<<<(NN + 63) / 64, 256, 0, stream>>>(node_features, Wn, bn, ts, ht_a);

  float* cur = ht_a;
  float* nxt = ht_b;
  for (int l = 0; l < NLAY; ++l) {
    k_msg<<<(NN + 63) / 64, 256, 0, stream>>>(cur, Wmp + l * HD * HD, bmp + l * HD,
                                              attn_a + l * (2 * HD + TDD), msgbf, p_src, p_dst);
    k_agg<<<(NN + 3) / 4, 256, 0, stream>>>(row_ptr, csr, p_src, p_dst, ta3 + l * NTT,
                                            msgbf, nxt, s_buf);
    float* tmp = cur; cur = nxt; nxt = tmp;
  }
  k_score<<<(NN + 63) / 64, 256, 0, stream>>>(cur, Wns1, qb, Wns2, bns2, Wes1,
                                              out_ns, out_h, Asrc, Adst);
  // 8 edges/wave, 4 waves/block => 32 edges per block
  k_edge<<<(NE + 31) / 32, 256, 0, stream>>>(src, dst, etype, Asrc, Adst, Te2,
                                             Wes2, bes2, out_es);
}

// Round 6
// 446.851 us; speedup vs baseline: 1.2542x; 1.2542x over previous
//
#include <hip/hip_runtime.h>
#include <math.h>

#define NN 50000
#define NE 800000
#define NFD 256
#define HD 64
#define QDD 128
#define TDD 32
#define NTT 64
#define NLAY 3
#define LCLAMP 6.1030340f   // atanh(1 - 1e-5)
#define CHUNK 1024
#define NCHUNK 49           // ceil(50000/1024)

typedef unsigned int uint;
typedef unsigned short ushort;
typedef __attribute__((ext_vector_type(8))) short bf16x8;
typedef __attribute__((ext_vector_type(4))) float f32x4;

__device__ __forceinline__ ushort f2bf(float f) {
  uint u = __float_as_uint(f);
  uint r = (u + 0x7FFFu + ((u >> 16) & 1u)) >> 16;
  return (ushort)r;
}
__device__ __forceinline__ short f2bfs(float f) { return (short)f2bf(f); }
__device__ __forceinline__ float bf2f(short s) { return __uint_as_float(((uint)(ushort)s) << 16); }
__device__ __forceinline__ float bflo(uint w) { return __uint_as_float(w << 16); }
__device__ __forceinline__ float bfhi(uint w) { return __uint_as_float(w & 0xFFFF0000u); }

// A-frag from 8 consecutive f32 (row-major activation row)
__device__ __forceinline__ bf16x8 frag_f32(const float* p) {
  float4 a = *(const float4*)p;
  float4 b = *(const float4*)(p + 4);
  bf16x8 r;
  r[0] = f2bfs(a.x); r[1] = f2bfs(a.y); r[2] = f2bfs(a.z); r[3] = f2bfs(a.w);
  r[4] = f2bfs(b.x); r[5] = f2bfs(b.y); r[6] = f2bfs(b.z); r[7] = f2bfs(b.w);
  return r;
}
// B-frag from row-major W[K][64]: k=k0+quad*8+j, n=j0+lane15
__device__ __forceinline__ bf16x8 bfrag_w(const float* W, int k0, int j0, int lane15, int quad) {
  bf16x8 r;
#pragma unroll
  for (int j = 0; j < 8; ++j) r[j] = f2bfs(W[(k0 + quad * 8 + j) * HD + j0 + lane15]);
  return r;
}

// ---------------------------------------------------------------- setup (small dense precomputes)
__global__ void k_setup(const float* __restrict__ edge_desc, const float* __restrict__ query,
                        const float* __restrict__ Wq, const float* __restrict__ bq,
                        const float* __restrict__ Ws, const float* __restrict__ bs,
                        const float* __restrict__ attn_a,
                        const float* __restrict__ Wns1, const float* __restrict__ bns1,
                        const float* __restrict__ Wes1, const float* __restrict__ bes1,
                        float* __restrict__ out_type_emb,
                        float* __restrict__ qb, float* __restrict__ ta3,
                        float* __restrict__ Te2) {
  __shared__ float te_l[NTT * TDD];
  __shared__ float q_l[HD];
  __shared__ float qe_l[HD];
  int t = threadIdx.x;
  if (t < HD) {
    float acc = bq[t];
    for (int k = 0; k < QDD; ++k) acc += query[k] * Wq[k * HD + t];
    q_l[t] = acc;
  }
  for (int idx = t; idx < NTT * TDD; idx += 256) {
    int ty = idx / TDD, d = idx % TDD;
    float acc = bs[d];
    for (int k = 0; k < 64; ++k) acc += edge_desc[ty * 64 + k] * Ws[k * TDD + d];
    float v = tanhf(acc);
    te_l[idx] = v;
    out_type_emb[idx] = v;
  }
  __syncthreads();
  if (t < NLAY * NTT) {
    int l = t / NTT, ty = t % NTT;
    float acc = 0.f;
    for (int d = 0; d < TDD; ++d) acc += te_l[ty * TDD + d] * attn_a[l * (2 * HD + TDD) + 2 * HD + d];
    ta3[t] = acc;
  }
  if (t < HD) {
    float a1 = bns1[t], a2 = bes1[t];
    for (int k = 0; k < HD; ++k) {
      a1 += q_l[k] * Wns1[(HD + k) * HD + t];
      a2 += q_l[k] * Wes1[(2 * HD + TDD + k) * HD + t];
    }
    qb[t] = a1;
    qe_l[t] = a2;
  }
  __syncthreads();
  for (int idx = t; idx < NTT * HD; idx += 256) {
    int ty = idx >> 6, j = idx & 63;
    float acc = qe_l[j];
    for (int d = 0; d < TDD; ++d) acc += te_l[ty * TDD + d] * Wes1[(2 * HD + d) * HD + j];
    Te2[idx] = acc;
  }
}

// ---------------------------------------------------------------- CSR build
__global__ void k_hist(const int* __restrict__ dst, int* __restrict__ cnt) {
  int e = blockIdx.x * 256 + threadIdx.x;
  if (e < NE) atomicAdd(&cnt[dst[e]], 1);
}

__global__ void k_scanA(const int* __restrict__ cnt, int* __restrict__ bsum) {
  __shared__ int ws[4];
  int t = threadIdx.x;
  int c0 = blockIdx.x * CHUNK;
  int s = 0;
#pragma unroll
  for (int it = 0; it < 4; ++it) {
    int i = c0 + it * 256 + t;
    if (i < NN) s += cnt[i];
  }
#pragma unroll
  for (int off = 1; off < 64; off <<= 1) s += __shfl_xor(s, off, 64);
  if ((t & 63) == 0) ws[t >> 6] = s;
  __syncthreads();
  if (t == 0) bsum[blockIdx.x] = ws[0] + ws[1] + ws[2] + ws[3];
}

__global__ void k_scanB(const int* __restrict__ bsum, int* __restrict__ boff,
                        int* __restrict__ row_ptr) {
  int t = threadIdx.x;  // 64 threads
  int v = (t < NCHUNK) ? bsum[t] : 0;
  int x = v;
#pragma unroll
  for (int off = 1; off < 64; off <<= 1) {
    int y = __shfl_up(x, off, 64);
    if (t >= off) x += y;
  }
  if (t < NCHUNK) boff[t] = x - v;
  if (t == 63) row_ptr[NN] = x;
}

__global__ void k_scanC(const int* __restrict__ cnt, const int* __restrict__ boff,
                        int* __restrict__ row_ptr, int* __restrict__ cursor) {
  __shared__ int wsum[4], woff_s[4];
  int t = threadIdx.x;
  int c0 = blockIdx.x * CHUNK;
  int i0 = c0 + t * 4;
  int v0 = (i0 + 0 < NN) ? cnt[i0 + 0] : 0;
  int v1 = (i0 + 1 < NN) ? cnt[i0 + 1] : 0;
  int v2 = (i0 + 2 < NN) ? cnt[i0 + 2] : 0;
  int v3 = (i0 + 3 < NN) ? cnt[i0 + 3] : 0;
  int s4 = v0 + v1 + v2 + v3;
  int lane = t & 63, wid = t >> 6;
  int x = s4;
#pragma unroll
  for (int off = 1; off < 64; off <<= 1) {
    int y = __shfl_up(x, off, 64);
    if (lane >= off) x += y;
  }
  if (lane == 63) wsum[wid] = x;
  __syncthreads();
  if (t == 0) {
    int a = 0;
    for (int i = 0; i < 4; ++i) { woff_s[i] = a; a += wsum[i]; }
  }
  __syncthreads();
  int base = boff[blockIdx.x] + woff_s[wid] + (x - s4);
  int r0 = base, r1 = base + v0, r2 = r1 + v1, r3 = r2 + v2;
  if (i0 + 0 < NN) { row_ptr[i0 + 0] = r0; cursor[i0 + 0] = r0; }
  if (i0 + 1 < NN) { row_ptr[i0 + 1] = r1; cursor[i0 + 1] = r1; }
  if (i0 + 2 < NN) { row_ptr[i0 + 2] = r2; cursor[i0 + 2] = r2; }
  if (i0 + 3 < NN) { row_ptr[i0 + 3] = r3; cursor[i0 + 3] = r3; }
}

__global__ void k_scatter(const int* __restrict__ src, const int* __restrict__ dst,
                          const int* __restrict__ etype, int* __restrict__ cursor,
                          uint* __restrict__ csr) {
  int e = blockIdx.x * 256 + threadIdx.x;
  if (e < NE) {
    int d = dst[e];
    int pos = atomicAdd(&cursor[d], 1);
    csr[pos] = (uint)src[e] | ((uint)etype[e] << 16);
  }
}

// ---------------------------------------------------------------- initial projection (MFMA)
// ht0 = clamp_norm((X @ Wn + bn) * ts). wave = jtile (16 cols), block = 64 nodes.
__global__ void __launch_bounds__(256) k_proj(const float* __restrict__ X,
                                              const float* __restrict__ Wn,
                                              const float* __restrict__ bn,
                                              const float* __restrict__ ts_p,
                                              float* __restrict__ ht0) {
  __shared__ float st[64 * 68];
  int t = threadIdx.x;
  int lane = t & 63, wv = t >> 6;
  int lane15 = lane & 15, quad = lane >> 4;
  int n0 = blockIdx.x * 64;
  int j0 = wv * 16;
  bf16x8 B[8];
#pragma unroll
  for (int ks = 0; ks < 8; ++ks) B[ks] = bfrag_w(Wn, ks * 32, j0, lane15, quad);
  float ts = ts_p[0];
  float vb = bn[j0 + lane15];

  for (int mt = 0; mt < 4; ++mt) {
    int m0 = n0 + mt * 16;
    int row = m0 + lane15; if (row >= NN) row = NN - 1;
    f32x4 acc = {0.f, 0.f, 0.f, 0.f};
#pragma unroll
    for (int ks = 0; ks < 8; ++ks) {
      bf16x8 A = frag_f32(X + (size_t)row * NFD + ks * 32 + quad * 8);
      acc = __builtin_amdgcn_mfma_f32_16x16x32_bf16(A, B[ks], acc, 0, 0, 0);
    }
#pragma unroll
    for (int i = 0; i < 4; ++i) {
      int lrow = mt * 16 + quad * 4 + i;
      st[lrow * 68 + j0 + lane15] = (acc[i] + vb) * ts;
    }
  }
  __syncthreads();
  // norm + clamp + coalesced write; thread: row r = t>>2, part p = t&3
  int r = t >> 2, p = t & 3;
  const float* rp = &st[r * 68 + p * 16];
  float4 v0 = *(const float4*)(rp + 0);
  float4 v1 = *(const float4*)(rp + 4);
  float4 v2 = *(const float4*)(rp + 8);
  float4 v3 = *(const float4*)(rp + 12);
  float ssq = v0.x*v0.x + v0.y*v0.y + v0.z*v0.z + v0.w*v0.w
            + v1.x*v1.x + v1.y*v1.y + v1.z*v1.z + v1.w*v1.w
            + v2.x*v2.x + v2.y*v2.y + v2.z*v2.z + v2.w*v2.w
            + v3.x*v3.x + v3.y*v3.y + v3.z*v3.z + v3.w*v3.w;
  ssq += __shfl_xor(ssq, 1, 64);
  ssq += __shfl_xor(ssq, 2, 64);
  float nu = fmaxf(sqrtf(ssq), 1e-15f);
  float sc = fminf(nu, LCLAMP) / nu;
  int grow = n0 + r;
  if (grow < NN) {
    float* op = &ht0[(size_t)grow * HD + p * 16];
    *(float4*)(op + 0)  = make_float4(v0.x*sc, v0.y*sc, v0.z*sc, v0.w*sc);
    *(float4*)(op + 4)  = make_float4(v1.x*sc, v1.y*sc, v1.z*sc, v1.w*sc);
    *(float4*)(op + 8)  = make_float4(v2.x*sc, v2.y*sc, v2.z*sc, v2.w*sc);
    *(float4*)(op + 12) = make_float4(v3.x*sc, v3.y*sc, v3.z*sc, v3.w*sc);
  }
}

// ---------------------------------------------------------------- msg = ht @ Wmp + bmp (bf16); p_src/p_dst (MFMA)
// wave = 16 nodes; 8 resident B-frags; 8 MFMAs.
__global__ void __launch_bounds__(256) k_msg(const float* __restrict__ ht,
                                             const float* __restrict__ Wmp_l,
                                             const float* __restrict__ bmp_l,
                                             const float* __restrict__ attn_l,
                                             ushort* __restrict__ msgbf,
                                             float* __restrict__ p_src,
                                             float* __restrict__ p_dst) {
  int t = threadIdx.x;
  int lane = t & 63, wv = t >> 6;
  int lane15 = lane & 15, quad = lane >> 4;
  int m0 = blockIdx.x * 64 + wv * 16;
  bf16x8 B[4][2];
  float vb[4];
#pragma unroll
  for (int jt = 0; jt < 4; ++jt) {
    B[jt][0] = bfrag_w(Wmp_l, 0, jt * 16, lane15, quad);
    B[jt][1] = bfrag_w(Wmp_l, 32, jt * 16, lane15, quad);
    vb[jt] = bmp_l[jt * 16 + lane15];
  }
  int row = m0 + lane15;
  int rowc = row < NN ? row : NN - 1;
  bf16x8 A0 = frag_f32(ht + (size_t)rowc * HD + quad * 8);
  bf16x8 A1 = frag_f32(ht + (size_t)rowc * HD + 32 + quad * 8);
  f32x4 acc[4];
#pragma unroll
  for (int jt = 0; jt < 4; ++jt) {
    f32x4 z = {0.f, 0.f, 0.f, 0.f};
    z = __builtin_amdgcn_mfma_f32_16x16x32_bf16(A0, B[jt][0], z, 0, 0, 0);
    z = __builtin_amdgcn_mfma_f32_16x16x32_bf16(A1, B[jt][1], z, 0, 0, 0);
    acc[jt] = z;
  }
#pragma unroll
  for (int jt = 0; jt < 4; ++jt)
#pragma unroll
    for (int i = 0; i < 4; ++i) {
      int r = m0 + quad * 4 + i;
      if (r < NN) msgbf[(size_t)r * HD + jt * 16 + lane15] = f2bf(acc[jt][i] + vb[jt]);
    }
  // p_src/p_dst from A-frags
  float4 a1l = *(const float4*)&attn_l[quad * 8];
  float4 a1h = *(const float4*)&attn_l[quad * 8 + 4];
  float4 a1l2 = *(const float4*)&attn_l[32 + quad * 8];
  float4 a1h2 = *(const float4*)&attn_l[32 + quad * 8 + 4];
  float4 a2l = *(const float4*)&attn_l[64 + quad * 8];
  float4 a2h = *(const float4*)&attn_l[64 + quad * 8 + 4];
  float4 a2l2 = *(const float4*)&attn_l[96 + quad * 8];
  float4 a2h2 = *(const float4*)&attn_l[96 + quad * 8 + 4];
  float p1 = bf2f(A0[0])*a1l.x + bf2f(A0[1])*a1l.y + bf2f(A0[2])*a1l.z + bf2f(A0[3])*a1l.w
           + bf2f(A0[4])*a1h.x + bf2f(A0[5])*a1h.y + bf2f(A0[6])*a1h.z + bf2f(A0[7])*a1h.w
           + bf2f(A1[0])*a1l2.x + bf2f(A1[1])*a1l2.y + bf2f(A1[2])*a1l2.z + bf2f(A1[3])*a1l2.w
           + bf2f(A1[4])*a1h2.x + bf2f(A1[5])*a1h2.y + bf2f(A1[6])*a1h2.z + bf2f(A1[7])*a1h2.w;
  float p2 = bf2f(A0[0])*a2l.x + bf2f(A0[1])*a2l.y + bf2f(A0[2])*a2l.z + bf2f(A0[3])*a2l.w
           + bf2f(A0[4])*a2h.x + bf2f(A0[5])*a2h.y + bf2f(A0[6])*a2h.z + bf2f(A0[7])*a2h.w
           + bf2f(A1[0])*a2l2.x + bf2f(A1[1])*a2l2.y + bf2f(A1[2])*a2l2.z + bf2f(A1[3])*a2l2.w
           + bf2f(A1[4])*a2h2.x + bf2f(A1[5])*a2h2.y + bf2f(A1[6])*a2h2.z + bf2f(A1[7])*a2h2.w;
  p1 += __shfl_xor(p1, 16, 64); p1 += __shfl_xor(p1, 32, 64);
  p2 += __shfl_xor(p2, 16, 64); p2 += __shfl_xor(p2, 32, 64);
  if (quad == 0 && row < NN) { p_src[row] = p1; p_dst[row] = p2; }
}

// ---------------------------------------------------------------- softmax-aggregate (wave/node, 8-wide gather)
__global__ void __launch_bounds__(256) k_agg(const int* __restrict__ row_ptr,
                                             const uint* __restrict__ csr,
                                             const float* __restrict__ p_src,
                                             const float* __restrict__ p_dst,
                                             const float* __restrict__ ta_l,
                                             const ushort* __restrict__ msgbf,
                                             float* __restrict__ ht_out,
                                             float* __restrict__ s_buf) {
  int lane = threadIdx.x & 63;
  int n = (blockIdx.x * 256 + threadIdx.x) >> 6;
  if (n >= NN) return;
  int start = row_ptr[n], end = row_ptr[n + 1];
  int deg = end - start;
  float pd = p_dst[n];
  int lq = lane & 7, lg = lane >> 3;
  float acc[8];
#pragma unroll
  for (int u = 0; u < 8; ++u) acc[u] = 0.f;
  float exsum = 0.f;

  if (deg <= 64) {
    bool valid = lane < deg;
    float s = -3.4e38f;
    int sidx = 0;
    if (valid) {
      uint pk = csr[start + lane];
      sidx = (int)(pk & 0xFFFFu);
      int ty = (int)(pk >> 16);
      float v = p_src[sidx] + pd + ta_l[ty];
      s = (v > 0.f) ? v : 0.2f * v;
    }
    float m = s;
#pragma unroll
    for (int off = 32; off >= 1; off >>= 1) m = fmaxf(m, __shfl_xor(m, off, 64));
    float ex = valid ? __expf(s - m) : 0.f;
    exsum = ex;
    for (int it = 0; it < deg; it += 8) {
      int el = it + lg;
      float exk = __shfl(ex, el, 64);
      int sk = __shfl(sidx, el, 64);
      if (el < deg) {
        uint4 mv = *(const uint4*)&msgbf[(size_t)sk * HD + lq * 8];
        acc[0] += exk * bflo(mv.x); acc[1] += exk * bfhi(mv.x);
        acc[2] += exk * bflo(mv.y); acc[3] += exk * bfhi(mv.y);
        acc[4] += exk * bflo(mv.z); acc[5] += exk * bfhi(mv.z);
        acc[6] += exk * bflo(mv.w); acc[7] += exk * bfhi(mv.w);
      }
    }
  } else {
    float m = -3.4e38f;
    for (int base = start; base < end; base += 64) {
      int i = base + lane;
      float s = -3.4e38f;
      if (i < end) {
        uint pk = csr[i];
        int sidx = (int)(pk & 0xFFFFu);
        int ty = (int)(pk >> 16);
        float v = p_src[sidx] + pd + ta_l[ty];
        s = (v > 0.f) ? v : 0.2f * v;
        s_buf[i] = s;
      }
      m = fmaxf(m, s);
    }
#pragma unroll
    for (int off = 32; off >= 1; off >>= 1) m = fmaxf(m, __shfl_xor(m, off, 64));
    for (int base = start; base < end; base += 64) {
      int i = base + lane;
      if (i < end) {
        float ex = __expf(s_buf[i] - m);
        s_buf[i] = ex;
        exsum += ex;
      }
    }
    for (int it = start; it < end; it += 8) {
      int el = it + lg;
      if (el < end) {
        float exk = s_buf[el];
        int sk = (int)(csr[el] & 0xFFFFu);
        uint4 mv = *(const uint4*)&msgbf[(size_t)sk * HD + lq * 8];
        acc[0] += exk * bflo(mv.x); acc[1] += exk * bfhi(mv.x);
        acc[2] += exk * bflo(mv.y); acc[3] += exk * bfhi(mv.y);
        acc[4] += exk * bflo(mv.z); acc[5] += exk * bfhi(mv.z);
        acc[6] += exk * bflo(mv.w); acc[7] += exk * bfhi(mv.w);
      }
    }
  }
#pragma unroll
  for (int u = 0; u < 8; ++u) {
    acc[u] += __shfl_xor(acc[u], 8, 64);
    acc[u] += __shfl_xor(acc[u], 16, 64);
    acc[u] += __shfl_xor(acc[u], 32, 64);
  }
#pragma unroll
  for (int off = 32; off >= 1; off >>= 1) exsum += __shfl_xor(exsum, off, 64);
  float inv = 1.f / (exsum + 1e-15f);
  float ss = 0.f;
#pragma unroll
  for (int u = 0; u < 8; ++u) {
    float v = fmaxf(acc[u] * inv, 0.f);
    acc[u] = v;
    ss += v * v;
  }
  ss += __shfl_xor(ss, 1, 64);
  ss += __shfl_xor(ss, 2, 64);
  ss += __shfl_xor(ss, 4, 64);
  float nu = fmaxf(sqrtf(ss), 1e-15f);
  float sc = fminf(nu, LCLAMP) / nu;
  if (lane < 8) {
    *(float4*)&ht_out[(size_t)n * HD + lane * 8] =
        make_float4(acc[0] * sc, acc[1] * sc, acc[2] * sc, acc[3] * sc);
    *(float4*)&ht_out[(size_t)n * HD + lane * 8 + 4] =
        make_float4(acc[4] * sc, acc[5] * sc, acc[6] * sc, acc[7] * sc);
  }
}

// ---------------------------------------------------------------- heads (MFMA): node score, Asrc/Adst, h_out
__global__ void __launch_bounds__(256) k_score(const float* __restrict__ ht,
                                               const float* __restrict__ Wns1,
                                               const float* __restrict__ qb,
                                               const float* __restrict__ Wns2,
                                               const float* __restrict__ bns2,
                                               const float* __restrict__ Wes1,
                                               float* __restrict__ node_scores,
                                               float* __restrict__ h_out,
                                               ushort* __restrict__ Asrc,
                                               ushort* __restrict__ Adst) {
  int t = threadIdx.x;
  int lane = t & 63, wv = t >> 6;
  int lane15 = lane & 15, quad = lane >> 4;
  int n0 = blockIdx.x * 64;
  int m0 = n0 + wv * 16;
  int row = m0 + lane15;
  int rowc = row < NN ? row : NN - 1;
  bf16x8 A0 = frag_f32(ht + (size_t)rowc * HD + quad * 8);
  bf16x8 A1 = frag_f32(ht + (size_t)rowc * HD + 32 + quad * 8);

  // ---- node head
  {
    f32x4 acc[4];
#pragma unroll
    for (int jt = 0; jt < 4; ++jt) {
      bf16x8 b0 = bfrag_w(Wns1, 0, jt * 16, lane15, quad);
      bf16x8 b1 = bfrag_w(Wns1, 32, jt * 16, lane15, quad);
      f32x4 z = {0.f, 0.f, 0.f, 0.f};
      z = __builtin_amdgcn_mfma_f32_16x16x32_bf16(A0, b0, z, 0, 0, 0);
      z = __builtin_amdgcn_mfma_f32_16x16x32_bf16(A1, b1, z, 0, 0, 0);
      acc[jt] = z;
    }
    float vqb[4], vw2[4];
#pragma unroll
    for (int jt = 0; jt < 4; ++jt) { vqb[jt] = qb[jt * 16 + lane15]; vw2[jt] = Wns2[jt * 16 + lane15]; }
    float b2 = bns2[0];
#pragma unroll
    for (int i = 0; i < 4; ++i) {
      float si = 0.f;
#pragma unroll
      for (int jt = 0; jt < 4; ++jt) si += fmaxf(acc[jt][i] + vqb[jt], 0.f) * vw2[jt];
      si += __shfl_xor(si, 1, 64);
      si += __shfl_xor(si, 2, 64);
      si += __shfl_xor(si, 4, 64);
      si += __shfl_xor(si, 8, 64);
      int r = m0 + quad * 4 + i;
      if (lane15 == 0 && r < NN) node_scores[r] = 1.f / (1.f + __expf(-(si + b2)));
    }
  }
  // ---- Asrc (Wes1 rows 0..63)
  {
#pragma unroll
    for (int jt = 0; jt < 4; ++jt) {
      bf16x8 b0 = bfrag_w(Wes1, 0, jt * 16, lane15, quad);
      bf16x8 b1 = bfrag_w(Wes1, 32, jt * 16, lane15, quad);
      f32x4 z = {0.f, 0.f, 0.f, 0.f};
      z = __builtin_amdgcn_mfma_f32_16x16x32_bf16(A0, b0, z, 0, 0, 0);
      z = __builtin_amdgcn_mfma_f32_16x16x32_bf16(A1, b1, z, 0, 0, 0);
#pragma unroll
      for (int i = 0; i < 4; ++i) {
        int r = m0 + quad * 4 + i;
        if (r < NN) Asrc[(size_t)r * HD + jt * 16 + lane15] = f2bf(z[i]);
      }
    }
  }
  // ---- Adst (Wes1 rows 64..127)
  {
    const float* W = Wes1 + 64 * HD;
#pragma unroll
    for (int jt = 0; jt < 4; ++jt) {
      bf16x8 b0 = bfrag_w(W, 0, jt * 16, lane15, quad);
      bf16x8 b1 = bfrag_w(W, 32, jt * 16, lane15, quad);
      f32x4 z = {0.f, 0.f, 0.f, 0.f};
      z = __builtin_amdgcn_mfma_f32_16x16x32_bf16(A0, b0, z, 0, 0, 0);
      z = __builtin_amdgcn_mfma_f32_16x16x32_bf16(A1, b1, z, 0, 0, 0);
#pragma unroll
      for (int i = 0; i < 4; ++i) {
        int r = m0 + quad * 4 + i;
        if (r < NN) Adst[(size_t)r * HD + jt * 16 + lane15] = f2bf(z[i]);
      }
    }
  }
  // ---- h_out: exact f32 pass; thread: row r=t>>2, part p=t&3 (independent, no sync needed)
  {
    int r = t >> 2, p = t & 3;
    int gr = n0 + r;
    int grc = gr < NN ? gr : NN - 1;
    const float* rp = ht + (size_t)grc * HD + p * 16;
    float4 v0 = *(const float4*)(rp + 0);
    float4 v1 = *(const float4*)(rp + 4);
    float4 v2 = *(const float4*)(rp + 8);
    float4 v3 = *(const float4*)(rp + 12);
    float ssq = v0.x*v0.x + v0.y*v0.y + v0.z*v0.z + v0.w*v0.w
              + v1.x*v1.x + v1.y*v1.y + v1.z*v1.z + v1.w*v1.w
              + v2.x*v2.x + v2.y*v2.y + v2.z*v2.z + v2.w*v2.w
              + v3.x*v3.x + v3.y*v3.y + v3.z*v3.z + v3.w*v3.w;
    ssq += __shfl_xor(ssq, 1, 64);
    ssq += __shfl_xor(ssq, 2, 64);
    float nu = fmaxf(sqrtf(ssq), 1e-15f);
    float hs = tanhf(nu) / nu;
    if (gr < NN) {
      float* op = h_out + (size_t)gr * HD + p * 16;
      *(float4*)(op + 0)  = make_float4(v0.x*hs, v0.y*hs, v0.z*hs, v0.w*hs);
      *(float4*)(op + 4)  = make_float4(v1.x*hs, v1.y*hs, v1.z*hs, v1.w*hs);
      *(float4*)(op + 8)  = make_float4(v2.x*hs, v2.y*hs, v2.z*hs, v2.w*hs);
      *(float4*)(op + 12) = make_float4(v3.x*hs, v3.y*hs, v3.z*hs, v3.w*hs);
    }
  }
}

// ---------------------------------------------------------------- edge scores (8 lanes/edge, 8 edges/wave)
__global__ void __launch_bounds__(256) k_edge(const int* __restrict__ src,
                                              const int* __restrict__ dst,
                                              const int* __restrict__ etype,
                                              const ushort* __restrict__ Asrc,
                                              const ushort* __restrict__ Adst,
                                              const float* __restrict__ Te2,
                                              const float* __restrict__ Wes2,
                                              const float* __restrict__ bes2,
                                              float* __restrict__ edge_scores) {
  int t = threadIdx.x;
  int lane = t & 63;
  int lq = lane & 7, lg = lane >> 3;
  int w = (blockIdx.x * 256 + t) >> 6;
  int e = w * 8 + lg;
  float p = 0.f;
  if (e < NE) {
    int si = src[e], di = dst[e], ti = etype[e];
    uint4 av = *(const uint4*)&Asrc[(size_t)si * HD + lq * 8];
    uint4 bv = *(const uint4*)&Adst[(size_t)di * HD + lq * 8];
    const float* tp = &Te2[ti * HD + lq * 8];
    float4 t0 = *(const float4*)tp;
    float4 t1 = *(const float4*)(tp + 4);
    const float* wp = &Wes2[lq * 8];
    float4 w0 = *(const float4*)wp;
    float4 w1 = *(const float4*)(wp + 4);
    p += fmaxf(bflo(av.x) + bflo(bv.x) + t0.x, 0.f) * w0.x;
    p += fmaxf(bfhi(av.x) + bfhi(bv.x) + t0.y, 0.f) * w0.y;
    p += fmaxf(bflo(av.y) + bflo(bv.y) + t0.z, 0.f) * w0.z;
    p += fmaxf(bfhi(av.y) + bfhi(bv.y) + t0.w, 0.f) * w0.w;
    p += fmaxf(bflo(av.z) + bflo(bv.z) + t1.x, 0.f) * w1.x;
    p += fmaxf(bfhi(av.z) + bfhi(bv.z) + t1.y, 0.f) * w1.y;
    p += fmaxf(bflo(av.w) + bflo(bv.w) + t1.z, 0.f) * w1.z;
    p += fmaxf(bfhi(av.w) + bfhi(bv.w) + t1.w, 0.f) * w1.w;
  }
  p += __shfl_xor(p, 1, 64);
  p += __shfl_xor(p, 2, 64);
  p += __shfl_xor(p, 4, 64);
  if (e < NE && lq == 0) edge_scores[e] = 1.f / (1.f + __expf(-(p + bes2[0])));
}

// ---------------------------------------------------------------- launch
extern "C" void kernel_launch(void* const* d_in, const int* in_sizes, int n_in,
                              void* d_out, int out_size, void* d_ws, size_t ws_size,
                              hipStream_t stream) {
  const float* node_features = (const float*)d_in[0];
  const float* edge_desc = (const float*)d_in[1];
  const float* query = (const float*)d_in[2];
  const float* Wn = (const float*)d_in[3];
  const float* bn = (const float*)d_in[4];
  const float* ts = (const float*)d_in[5];
  const float* Wq = (const float*)d_in[6];
  const float* bq = (const float*)d_in[7];
  const float* Ws_ = (const float*)d_in[8];
  const float* bs = (const float*)d_in[9];
  const float* attn_a = (const float*)d_in[10];
  const float* Wmp = (const float*)d_in[11];
  const float* bmp = (const float*)d_in[12];
  const float* Wns1 = (const float*)d_in[13];
  const float* bns1 = (const float*)d_in[14];
  const float* Wns2 = (const float*)d_in[15];
  const float* bns2 = (const float*)d_in[16];
  const float* Wes1 = (const float*)d_in[17];
  const float* bes1 = (const float*)d_in[18];
  const float* Wes2 = (const float*)d_in[19];
  const float* bes2 = (const float*)d_in[20];
  const int* edge_index = (const int*)d_in[21];
  const int* etype = (const int*)d_in[22];
  const int* src = edge_index;
  const int* dst = edge_index + NE;

  float* out_ns = (float*)d_out;
  float* out_es = out_ns + NN;
  float* out_h = out_es + NE;
  float* out_te = out_h + (size_t)NN * HD;

  char* w = (char*)d_ws;
  auto alloc = [&](size_t bytes) {
    char* p = w;
    w += (bytes + 1023) & ~(size_t)1023;
    return p;
  };
  float* ht_a = (float*)alloc((size_t)NN * HD * 4);
  float* ht_b = (float*)alloc((size_t)NN * HD * 4);
  ushort* msgbf = (ushort*)alloc((size_t)NN * HD * 2);
  ushort* Asrc = (ushort*)alloc((size_t)NN * HD * 2);
  ushort* Adst = (ushort*)alloc((size_t)NN * HD * 2);
  float* p_src = (float*)alloc(NN * 4);
  float* p_dst = (float*)alloc(NN * 4);
  float* s_buf = (float*)alloc(NE * 4);
  float* qb = (float*)alloc(HD * 4);
  float* ta3 = (float*)alloc(NLAY * NTT * 4);
  float* Te2 = (float*)alloc(NTT * HD * 4);
  int* cnt = (int*)alloc(NN * 4);
  int* row_ptr = (int*)alloc((NN + 1) * 4);
  int* cursor = (int*)alloc(NN * 4);
  int* bsum = (int*)alloc(NCHUNK * 4);
  int* boff = (int*)alloc(NCHUNK * 4);
  uint* csr = (uint*)alloc(NE * 4);

  hipMemsetAsync(cnt, 0, NN * 4, stream);
  k_setup<<<1, 256, 0, stream>>>(edge_desc, query, Wq, bq, Ws_, bs, attn_a, Wns1, bns1,
                                 Wes1, bes1, out_te, qb, ta3, Te2);
  k_hist<<<NE / 256, 256, 0, stream>>>(dst, cnt);
  k_scanA<<<NCHUNK, 256, 0, stream>>>(cnt, bsum);
  k_scanB<<<1, 64, 0, stream>>>(bsum, boff, row_ptr);
  k_scanC<<<NCHUNK, 256, 0, stream>>>(cnt, boff, row_ptr, cursor);
  k_scatter<<<NE / 256, 256, 0, stream>>>(src, dst, etype, cursor, csr);
  k_proj<<<(NN + 63) / 64, 256, 0, stream>>>(node_features, Wn, bn, ts, ht_a);

  float* cur = ht_a;
  float* nxt = ht_b;
  for (int l = 0; l < NLAY; ++l) {
    k_msg<<<(NN + 63) / 64, 256, 0, stream>>>(cur, Wmp + l * HD * HD, bmp + l * HD,
                                              attn_a + l * (2 * HD + TDD), msgbf, p_src, p_dst);
    k_agg<<<(NN + 3) / 4, 256, 0, stream>>>(row_ptr, csr, p_src, p_dst, ta3 + l * NTT,
                                            msgbf, nxt, s_buf);
    float* tmp = cur; cur = nxt; nxt = tmp;
  }
  k_score<<<(NN + 63) / 64, 256, 0, stream>>>(cur, Wns1, qb, Wns2, bns2, Wes1,
                                              out_ns, out_h, Asrc, Adst);
  // 8 edges/wave, 4 waves/block => 32 edges per block
  k_edge<<<(NE + 31) / 32, 256, 0, stream>>>(src, dst, etype, Asrc, Adst, Te2,
                                             Wes2, bes2, out_es);
}

// Round 7
// 431.892 us; speedup vs baseline: 1.2977x; 1.0346x over previous
//
#include <hip/hip_runtime.h>
#include <math.h>

#define NN 50000
#define NE 800000
#define NFD 256
#define HD 64
#define QDD 128
#define TDD 32
#define NTT 64
#define NLAY 3
#define LCLAMP 6.1030340f   // atanh(1 - 1e-5)
#define CHUNK 1024
#define NCHUNK 49           // ceil(50000/1024)
#define NBUCK 196           // ceil(50000/256) coarse buckets (dst >> 8)
#define EPB 2048            // edges per k_bin block
#define NBINBLK 391         // ceil(800000/2048)

typedef unsigned int uint;
typedef unsigned short ushort;
typedef __attribute__((ext_vector_type(8))) short bf16x8;
typedef __attribute__((ext_vector_type(4))) float f32x4;

__device__ __forceinline__ ushort f2bf(float f) {
  uint u = __float_as_uint(f);
  uint r = (u + 0x7FFFu + ((u >> 16) & 1u)) >> 16;
  return (ushort)r;
}
__device__ __forceinline__ short f2bfs(float f) { return (short)f2bf(f); }
__device__ __forceinline__ float bf2f(short s) { return __uint_as_float(((uint)(ushort)s) << 16); }
__device__ __forceinline__ float bflo(uint w) { return __uint_as_float(w << 16); }
__device__ __forceinline__ float bfhi(uint w) { return __uint_as_float(w & 0xFFFF0000u); }

// A-frag from 8 consecutive f32 (row-major activation row)
__device__ __forceinline__ bf16x8 frag_f32(const float* p) {
  float4 a = *(const float4*)p;
  float4 b = *(const float4*)(p + 4);
  bf16x8 r;
  r[0] = f2bfs(a.x); r[1] = f2bfs(a.y); r[2] = f2bfs(a.z); r[3] = f2bfs(a.w);
  r[4] = f2bfs(b.x); r[5] = f2bfs(b.y); r[6] = f2bfs(b.z); r[7] = f2bfs(b.w);
  return r;
}
// B-frag from row-major W[K][64]: k=k0+quad*8+j, n=j0+lane15
__device__ __forceinline__ bf16x8 bfrag_w(const float* W, int k0, int j0, int lane15, int quad) {
  bf16x8 r;
#pragma unroll
  for (int j = 0; j < 8; ++j) r[j] = f2bfs(W[(k0 + quad * 8 + j) * HD + j0 + lane15]);
  return r;
}

// ---------------------------------------------------------------- setup (small dense precomputes)
__global__ void k_setup(const float* __restrict__ edge_desc, const float* __restrict__ query,
                        const float* __restrict__ Wq, const float* __restrict__ bq,
                        const float* __restrict__ Ws, const float* __restrict__ bs,
                        const float* __restrict__ attn_a,
                        const float* __restrict__ Wns1, const float* __restrict__ bns1,
                        const float* __restrict__ Wes1, const float* __restrict__ bes1,
                        float* __restrict__ out_type_emb,
                        float* __restrict__ qb, float* __restrict__ ta3,
                        float* __restrict__ qe) {
  __shared__ float te_l[NTT * TDD];
  __shared__ float q_l[HD];
  int t = threadIdx.x;
  if (t < HD) {
    float acc = bq[t];
    for (int k = 0; k < QDD; ++k) acc += query[k] * Wq[k * HD + t];
    q_l[t] = acc;
  }
  for (int idx = t; idx < NTT * TDD; idx += 256) {
    int ty = idx / TDD, d = idx % TDD;
    float acc = bs[d];
    for (int k = 0; k < 64; ++k) acc += edge_desc[ty * 64 + k] * Ws[k * TDD + d];
    float v = tanhf(acc);
    te_l[idx] = v;
    out_type_emb[idx] = v;
  }
  __syncthreads();
  if (t < NLAY * NTT) {
    int l = t / NTT, ty = t % NTT;
    float acc = 0.f;
    for (int d = 0; d < TDD; ++d) acc += te_l[ty * TDD + d] * attn_a[l * (2 * HD + TDD) + 2 * HD + d];
    ta3[t] = acc;
  }
  if (t < HD) {
    float a1 = bns1[t], a2 = bes1[t];
    for (int k = 0; k < HD; ++k) {
      a1 += q_l[k] * Wns1[(HD + k) * HD + t];
      a2 += q_l[k] * Wes1[(2 * HD + TDD + k) * HD + t];
    }
    qb[t] = a1;
    qe[t] = a2;
  }
}

// Te2[ty][j] = type_emb[ty] @ Wes1[te-part] + qe (bias folded); 16 blocks x 256
__global__ void k_te2(const float* __restrict__ te, const float* __restrict__ qe,
                      const float* __restrict__ Wes1, float* __restrict__ Te2) {
  int idx = blockIdx.x * 256 + threadIdx.x;   // 4096 total
  int ty = idx >> 6, j = idx & 63;
  float acc = qe[j];
#pragma unroll
  for (int d = 0; d < TDD; ++d) acc += te[ty * TDD + d] * Wes1[(2 * HD + d) * HD + j];
  Te2[idx] = acc;
}

// ---------------------------------------------------------------- CSR build
__global__ void k_hist(const int* __restrict__ dst, int* __restrict__ cnt) {
  int e = blockIdx.x * 256 + threadIdx.x;
  if (e < NE) atomicAdd(&cnt[dst[e]], 1);
}

__global__ void k_scanA(const int* __restrict__ cnt, int* __restrict__ bsum) {
  __shared__ int ws[4];
  int t = threadIdx.x;
  int c0 = blockIdx.x * CHUNK;
  int s = 0;
#pragma unroll
  for (int it = 0; it < 4; ++it) {
    int i = c0 + it * 256 + t;
    if (i < NN) s += cnt[i];
  }
#pragma unroll
  for (int off = 1; off < 64; off <<= 1) s += __shfl_xor(s, off, 64);
  if ((t & 63) == 0) ws[t >> 6] = s;
  __syncthreads();
  if (t == 0) bsum[blockIdx.x] = ws[0] + ws[1] + ws[2] + ws[3];
}

__global__ void k_scanB(const int* __restrict__ bsum, int* __restrict__ boff,
                        int* __restrict__ row_ptr) {
  int t = threadIdx.x;  // 64 threads
  int v = (t < NCHUNK) ? bsum[t] : 0;
  int x = v;
#pragma unroll
  for (int off = 1; off < 64; off <<= 1) {
    int y = __shfl_up(x, off, 64);
    if (t >= off) x += y;
  }
  if (t < NCHUNK) boff[t] = x - v;
  if (t == 63) row_ptr[NN] = x;
}

__global__ void k_scanC(const int* __restrict__ cnt, const int* __restrict__ boff,
                        int* __restrict__ row_ptr, int* __restrict__ cursor) {
  __shared__ int wsum[4], woff_s[4];
  int t = threadIdx.x;
  int c0 = blockIdx.x * CHUNK;
  int i0 = c0 + t * 4;
  int v0 = (i0 + 0 < NN) ? cnt[i0 + 0] : 0;
  int v1 = (i0 + 1 < NN) ? cnt[i0 + 1] : 0;
  int v2 = (i0 + 2 < NN) ? cnt[i0 + 2] : 0;
  int v3 = (i0 + 3 < NN) ? cnt[i0 + 3] : 0;
  int s4 = v0 + v1 + v2 + v3;
  int lane = t & 63, wid = t >> 6;
  int x = s4;
#pragma unroll
  for (int off = 1; off < 64; off <<= 1) {
    int y = __shfl_up(x, off, 64);
    if (lane >= off) x += y;
  }
  if (lane == 63) wsum[wid] = x;
  __syncthreads();
  if (t == 0) {
    int a = 0;
    for (int i = 0; i < 4; ++i) { woff_s[i] = a; a += wsum[i]; }
  }
  __syncthreads();
  int base = boff[blockIdx.x] + woff_s[wid] + (x - s4);
  int r0 = base, r1 = base + v0, r2 = r1 + v1, r3 = r2 + v2;
  if (i0 + 0 < NN) { row_ptr[i0 + 0] = r0; cursor[i0 + 0] = r0; }
  if (i0 + 1 < NN) { row_ptr[i0 + 1] = r1; cursor[i0 + 1] = r1; }
  if (i0 + 2 < NN) { row_ptr[i0 + 2] = r2; cursor[i0 + 2] = r2; }
  if (i0 + 3 < NN) { row_ptr[i0 + 3] = r3; cursor[i0 + 3] = r3; }
}

// bucket_cursor[b] = row_ptr[b*256]
__global__ void k_binit(const int* __restrict__ row_ptr, int* __restrict__ bucket_cursor) {
  int b = blockIdx.x * 256 + threadIdx.x;
  if (b < NBUCK) bucket_cursor[b] = row_ptr[b << 8];
}

// phase B: bin edges by coarse bucket (dst>>8) into ebuf (same layout as csr)
__global__ void __launch_bounds__(256) k_bin(const int* __restrict__ src,
                                             const int* __restrict__ dst,
                                             const int* __restrict__ etype,
                                             int* __restrict__ bucket_cursor,
                                             uint2* __restrict__ ebuf) {
  __shared__ int cntl[NBUCK];
  __shared__ int gbase[NBUCK];
  int t = threadIdx.x;
  for (int i = t; i < NBUCK; i += 256) cntl[i] = 0;
  __syncthreads();
  int e0 = blockIdx.x * EPB;
  int dd[8], pk[8], rk[8], bk[8];
#pragma unroll
  for (int i = 0; i < 8; ++i) {
    int e = e0 + t + i * 256;
    if (e < NE) {
      int d = dst[e];
      dd[i] = d;
      pk[i] = src[e] | (etype[e] << 16);
      bk[i] = d >> 8;
      rk[i] = atomicAdd(&cntl[bk[i]], 1);
    } else dd[i] = -1;
  }
  __syncthreads();
  if (t < NBUCK && cntl[t] > 0) gbase[t] = atomicAdd(&bucket_cursor[t], cntl[t]);
  __syncthreads();
#pragma unroll
  for (int i = 0; i < 8; ++i) {
    if (dd[i] >= 0) {
      int pos = gbase[bk[i]] + rk[i];
      ebuf[pos] = make_uint2((uint)pk[i], (uint)dd[i]);
    }
  }
}

// phase C: per-bucket scatter to final CSR position (writes L2-local, 16KB window)
__global__ void __launch_bounds__(256) k_scatter2(const int* __restrict__ row_ptr,
                                                  const uint2* __restrict__ ebuf,
                                                  int* __restrict__ cursor,
                                                  uint* __restrict__ csr) {
  int b = blockIdx.x;
  int n0 = b << 8;
  int n1 = n0 + 256; if (n1 > NN) n1 = NN;
  int lo = row_ptr[n0];
  int hi = row_ptr[n1];
  for (int i = lo + threadIdx.x; i < hi; i += 256) {
    uint2 r = ebuf[i];
    int pos = atomicAdd(&cursor[(int)r.y], 1);
    csr[pos] = r.x;
  }
}

// ---------------------------------------------------------------- initial projection (MFMA)
__global__ void __launch_bounds__(256) k_proj(const float* __restrict__ X,
                                              const float* __restrict__ Wn,
                                              const float* __restrict__ bn,
                                              const float* __restrict__ ts_p,
                                              float* __restrict__ ht0) {
  __shared__ float st[64 * 68];
  int t = threadIdx.x;
  int lane = t & 63, wv = t >> 6;
  int lane15 = lane & 15, quad = lane >> 4;
  int n0 = blockIdx.x * 64;
  int j0 = wv * 16;
  bf16x8 B[8];
#pragma unroll
  for (int ks = 0; ks < 8; ++ks) B[ks] = bfrag_w(Wn, ks * 32, j0, lane15, quad);
  float ts = ts_p[0];
  float vb = bn[j0 + lane15];

  for (int mt = 0; mt < 4; ++mt) {
    int m0 = n0 + mt * 16;
    int row = m0 + lane15; if (row >= NN) row = NN - 1;
    f32x4 acc = {0.f, 0.f, 0.f, 0.f};
#pragma unroll
    for (int ks = 0; ks < 8; ++ks) {
      bf16x8 A = frag_f32(X + (size_t)row * NFD + ks * 32 + quad * 8);
      acc = __builtin_amdgcn_mfma_f32_16x16x32_bf16(A, B[ks], acc, 0, 0, 0);
    }
#pragma unroll
    for (int i = 0; i < 4; ++i) {
      int lrow = mt * 16 + quad * 4 + i;
      st[lrow * 68 + j0 + lane15] = (acc[i] + vb) * ts;
    }
  }
  __syncthreads();
  int r = t >> 2, p = t & 3;
  const float* rp = &st[r * 68 + p * 16];
  float4 v0 = *(const float4*)(rp + 0);
  float4 v1 = *(const float4*)(rp + 4);
  float4 v2 = *(const float4*)(rp + 8);
  float4 v3 = *(const float4*)(rp + 12);
  float ssq = v0.x*v0.x + v0.y*v0.y + v0.z*v0.z + v0.w*v0.w
            + v1.x*v1.x + v1.y*v1.y + v1.z*v1.z + v1.w*v1.w
            + v2.x*v2.x + v2.y*v2.y + v2.z*v2.z + v2.w*v2.w
            + v3.x*v3.x + v3.y*v3.y + v3.z*v3.z + v3.w*v3.w;
  ssq += __shfl_xor(ssq, 1, 64);
  ssq += __shfl_xor(ssq, 2, 64);
  float nu = fmaxf(sqrtf(ssq), 1e-15f);
  float sc = fminf(nu, LCLAMP) / nu;
  int grow = n0 + r;
  if (grow < NN) {
    float* op = &ht0[(size_t)grow * HD + p * 16];
    *(float4*)(op + 0)  = make_float4(v0.x*sc, v0.y*sc, v0.z*sc, v0.w*sc);
    *(float4*)(op + 4)  = make_float4(v1.x*sc, v1.y*sc, v1.z*sc, v1.w*sc);
    *(float4*)(op + 8)  = make_float4(v2.x*sc, v2.y*sc, v2.z*sc, v2.w*sc);
    *(float4*)(op + 12) = make_float4(v3.x*sc, v3.y*sc, v3.z*sc, v3.w*sc);
  }
}

// ---------------------------------------------------------------- msg = ht @ Wmp + bmp (bf16); p_src/p_dst (MFMA)
__global__ void __launch_bounds__(256) k_msg(const float* __restrict__ ht,
                                             const float* __restrict__ Wmp_l,
                                             const float* __restrict__ bmp_l,
                                             const float* __restrict__ attn_l,
                                             ushort* __restrict__ msgbf,
                                             float* __restrict__ p_src,
                                             float* __restrict__ p_dst) {
  int t = threadIdx.x;
  int lane = t & 63, wv = t >> 6;
  int lane15 = lane & 15, quad = lane >> 4;
  int m0 = blockIdx.x * 64 + wv * 16;
  bf16x8 B[4][2];
  float vb[4];
#pragma unroll
  for (int jt = 0; jt < 4; ++jt) {
    B[jt][0] = bfrag_w(Wmp_l, 0, jt * 16, lane15, quad);
    B[jt][1] = bfrag_w(Wmp_l, 32, jt * 16, lane15, quad);
    vb[jt] = bmp_l[jt * 16 + lane15];
  }
  int row = m0 + lane15;
  int rowc = row < NN ? row : NN - 1;
  bf16x8 A0 = frag_f32(ht + (size_t)rowc * HD + quad * 8);
  bf16x8 A1 = frag_f32(ht + (size_t)rowc * HD + 32 + quad * 8);
  f32x4 acc[4];
#pragma unroll
  for (int jt = 0; jt < 4; ++jt) {
    f32x4 z = {0.f, 0.f, 0.f, 0.f};
    z = __builtin_amdgcn_mfma_f32_16x16x32_bf16(A0, B[jt][0], z, 0, 0, 0);
    z = __builtin_amdgcn_mfma_f32_16x16x32_bf16(A1, B[jt][1], z, 0, 0, 0);
    acc[jt] = z;
  }
#pragma unroll
  for (int jt = 0; jt < 4; ++jt)
#pragma unroll
    for (int i = 0; i < 4; ++i) {
      int r = m0 + quad * 4 + i;
      if (r < NN) msgbf[(size_t)r * HD + jt * 16 + lane15] = f2bf(acc[jt][i] + vb[jt]);
    }
  float4 a1l = *(const float4*)&attn_l[quad * 8];
  float4 a1h = *(const float4*)&attn_l[quad * 8 + 4];
  float4 a1l2 = *(const float4*)&attn_l[32 + quad * 8];
  float4 a1h2 = *(const float4*)&attn_l[32 + quad * 8 + 4];
  float4 a2l = *(const float4*)&attn_l[64 + quad * 8];
  float4 a2h = *(const float4*)&attn_l[64 + quad * 8 + 4];
  float4 a2l2 = *(const float4*)&attn_l[96 + quad * 8];
  float4 a2h2 = *(const float4*)&attn_l[96 + quad * 8 + 4];
  float p1 = bf2f(A0[0])*a1l.x + bf2f(A0[1])*a1l.y + bf2f(A0[2])*a1l.z + bf2f(A0[3])*a1l.w
           + bf2f(A0[4])*a1h.x + bf2f(A0[5])*a1h.y + bf2f(A0[6])*a1h.z + bf2f(A0[7])*a1h.w
           + bf2f(A1[0])*a1l2.x + bf2f(A1[1])*a1l2.y + bf2f(A1[2])*a1l2.z + bf2f(A1[3])*a1l2.w
           + bf2f(A1[4])*a1h2.x + bf2f(A1[5])*a1h2.y + bf2f(A1[6])*a1h2.z + bf2f(A1[7])*a1h2.w;
  float p2 = bf2f(A0[0])*a2l.x + bf2f(A0[1])*a2l.y + bf2f(A0[2])*a2l.z + bf2f(A0[3])*a2l.w
           + bf2f(A0[4])*a2h.x + bf2f(A0[5])*a2h.y + bf2f(A0[6])*a2h.z + bf2f(A0[7])*a2h.w
           + bf2f(A1[0])*a2l2.x + bf2f(A1[1])*a2l2.y + bf2f(A1[2])*a2l2.z + bf2f(A1[3])*a2l2.w
           + bf2f(A1[4])*a2h2.x + bf2f(A1[5])*a2h2.y + bf2f(A1[6])*a2h2.z + bf2f(A1[7])*a2h2.w;
  p1 += __shfl_xor(p1, 16, 64); p1 += __shfl_xor(p1, 32, 64);
  p2 += __shfl_xor(p2, 16, 64); p2 += __shfl_xor(p2, 32, 64);
  if (quad == 0 && row < NN) { p_src[row] = p1; p_dst[row] = p2; }
}

// ---------------------------------------------------------------- softmax-aggregate (wave/node, 8-wide gather)
__global__ void __launch_bounds__(256) k_agg(const int* __restrict__ row_ptr,
                                             const uint* __restrict__ csr,
                                             const float* __restrict__ p_src,
                                             const float* __restrict__ p_dst,
                                             const float* __restrict__ ta_l,
                                             const ushort* __restrict__ msgbf,
                                             float* __restrict__ ht_out,
                                             float* __restrict__ s_buf) {
  int lane = threadIdx.x & 63;
  int n = (blockIdx.x * 256 + threadIdx.x) >> 6;
  if (n >= NN) return;
  int start = row_ptr[n], end = row_ptr[n + 1];
  int deg = end - start;
  float pd = p_dst[n];
  int lq = lane & 7, lg = lane >> 3;
  float acc[8];
#pragma unroll
  for (int u = 0; u < 8; ++u) acc[u] = 0.f;
  float exsum = 0.f;

  if (deg <= 64) {
    bool valid = lane < deg;
    float s = -3.4e38f;
    int sidx = 0;
    if (valid) {
      uint pk = csr[start + lane];
      sidx = (int)(pk & 0xFFFFu);
      int ty = (int)(pk >> 16);
      float v = p_src[sidx] + pd + ta_l[ty];
      s = (v > 0.f) ? v : 0.2f * v;
    }
    float m = s;
#pragma unroll
    for (int off = 32; off >= 1; off >>= 1) m = fmaxf(m, __shfl_xor(m, off, 64));
    float ex = valid ? __expf(s - m) : 0.f;
    exsum = ex;
    for (int it = 0; it < deg; it += 8) {
      int el = it + lg;
      float exk = __shfl(ex, el, 64);
      int sk = __shfl(sidx, el, 64);
      if (el < deg) {
        uint4 mv = *(const uint4*)&msgbf[(size_t)sk * HD + lq * 8];
        acc[0] += exk * bflo(mv.x); acc[1] += exk * bfhi(mv.x);
        acc[2] += exk * bflo(mv.y); acc[3] += exk * bfhi(mv.y);
        acc[4] += exk * bflo(mv.z); acc[5] += exk * bfhi(mv.z);
        acc[6] += exk * bflo(mv.w); acc[7] += exk * bfhi(mv.w);
      }
    }
  } else {
    float m = -3.4e38f;
    for (int base = start; base < end; base += 64) {
      int i = base + lane;
      float s = -3.4e38f;
      if (i < end) {
        uint pk = csr[i];
        int sidx = (int)(pk & 0xFFFFu);
        int ty = (int)(pk >> 16);
        float v = p_src[sidx] + pd + ta_l[ty];
        s = (v > 0.f) ? v : 0.2f * v;
        s_buf[i] = s;
      }
      m = fmaxf(m, s);
    }
#pragma unroll
    for (int off = 32; off >= 1; off >>= 1) m = fmaxf(m, __shfl_xor(m, off, 64));
    for (int base = start; base < end; base += 64) {
      int i = base + lane;
      if (i < end) {
        float ex = __expf(s_buf[i] - m);
        s_buf[i] = ex;
        exsum += ex;
      }
    }
    for (int it = start; it < end; it += 8) {
      int el = it + lg;
      if (el < end) {
        float exk = s_buf[el];
        int sk = (int)(csr[el] & 0xFFFFu);
        uint4 mv = *(const uint4*)&msgbf[(size_t)sk * HD + lq * 8];
        acc[0] += exk * bflo(mv.x); acc[1] += exk * bfhi(mv.x);
        acc[2] += exk * bflo(mv.y); acc[3] += exk * bfhi(mv.y);
        acc[4] += exk * bflo(mv.z); acc[5] += exk * bfhi(mv.z);
        acc[6] += exk * bflo(mv.w); acc[7] += exk * bfhi(mv.w);
      }
    }
  }
#pragma unroll
  for (int u = 0; u < 8; ++u) {
    acc[u] += __shfl_xor(acc[u], 8, 64);
    acc[u] += __shfl_xor(acc[u], 16, 64);
    acc[u] += __shfl_xor(acc[u], 32, 64);
  }
#pragma unroll
  for (int off = 32; off >= 1; off >>= 1) exsum += __shfl_xor(exsum, off, 64);
  float inv = 1.f / (exsum + 1e-15f);
  float ss = 0.f;
#pragma unroll
  for (int u = 0; u < 8; ++u) {
    float v = fmaxf(acc[u] * inv, 0.f);
    acc[u] = v;
    ss += v * v;
  }
  ss += __shfl_xor(ss, 1, 64);
  ss += __shfl_xor(ss, 2, 64);
  ss += __shfl_xor(ss, 4, 64);
  float nu = fmaxf(sqrtf(ss), 1e-15f);
  float sc = fminf(nu, LCLAMP) / nu;
  if (lane < 8) {
    *(float4*)&ht_out[(size_t)n * HD + lane * 8] =
        make_float4(acc[0] * sc, acc[1] * sc, acc[2] * sc, acc[3] * sc);
    *(float4*)&ht_out[(size_t)n * HD + lane * 8 + 4] =
        make_float4(acc[4] * sc, acc[5] * sc, acc[6] * sc, acc[7] * sc);
  }
}

// ---------------------------------------------------------------- heads (MFMA): node score, Asrc/Adst, h_out
__global__ void __launch_bounds__(256) k_score(const float* __restrict__ ht,
                                               const float* __restrict__ Wns1,
                                               const float* __restrict__ qb,
                                               const float* __restrict__ Wns2,
                                               const float* __restrict__ bns2,
                                               const float* __restrict__ Wes1,
                                               float* __restrict__ node_scores,
                                               float* __restrict__ h_out,
                                               ushort* __restrict__ Asrc,
                                               ushort* __restrict__ Adst) {
  int t = threadIdx.x;
  int lane = t & 63, wv = t >> 6;
  int lane15 = lane & 15, quad = lane >> 4;
  int n0 = blockIdx.x * 64;
  int m0 = n0 + wv * 16;
  int row = m0 + lane15;
  int rowc = row < NN ? row : NN - 1;
  bf16x8 A0 = frag_f32(ht + (size_t)rowc * HD + quad * 8);
  bf16x8 A1 = frag_f32(ht + (size_t)rowc * HD + 32 + quad * 8);

  // ---- node head
  {
    f32x4 acc[4];
#pragma unroll
    for (int jt = 0; jt < 4; ++jt) {
      bf16x8 b0 = bfrag_w(Wns1, 0, jt * 16, lane15, quad);
      bf16x8 b1 = bfrag_w(Wns1, 32, jt * 16, lane15, quad);
      f32x4 z = {0.f, 0.f, 0.f, 0.f};
      z = __builtin_amdgcn_mfma_f32_16x16x32_bf16(A0, b0, z, 0, 0, 0);
      z = __builtin_amdgcn_mfma_f32_16x16x32_bf16(A1, b1, z, 0, 0, 0);
      acc[jt] = z;
    }
    float vqb[4], vw2[4];
#pragma unroll
    for (int jt = 0; jt < 4; ++jt) { vqb[jt] = qb[jt * 16 + lane15]; vw2[jt] = Wns2[jt * 16 + lane15]; }
    float b2 = bns2[0];
#pragma unroll
    for (int i = 0; i < 4; ++i) {
      float si = 0.f;
#pragma unroll
      for (int jt = 0; jt < 4; ++jt) si += fmaxf(acc[jt][i] + vqb[jt], 0.f) * vw2[jt];
      si += __shfl_xor(si, 1, 64);
      si += __shfl_xor(si, 2, 64);
      si += __shfl_xor(si, 4, 64);
      si += __shfl_xor(si, 8, 64);
      int r = m0 + quad * 4 + i;
      if (lane15 == 0 && r < NN) node_scores[r] = 1.f / (1.f + __expf(-(si + b2)));
    }
  }
  // ---- Asrc (Wes1 rows 0..63)
  {
#pragma unroll
    for (int jt = 0; jt < 4; ++jt) {
      bf16x8 b0 = bfrag_w(Wes1, 0, jt * 16, lane15, quad);
      bf16x8 b1 = bfrag_w(Wes1, 32, jt * 16, lane15, quad);
      f32x4 z = {0.f, 0.f, 0.f, 0.f};
      z = __builtin_amdgcn_mfma_f32_16x16x32_bf16(A0, b0, z, 0, 0, 0);
      z = __builtin_amdgcn_mfma_f32_16x16x32_bf16(A1, b1, z, 0, 0, 0);
#pragma unroll
      for (int i = 0; i < 4; ++i) {
        int r = m0 + quad * 4 + i;
        if (r < NN) Asrc[(size_t)r * HD + jt * 16 + lane15] = f2bf(z[i]);
      }
    }
  }
  // ---- Adst (Wes1 rows 64..127)
  {
    const float* W = Wes1 + 64 * HD;
#pragma unroll
    for (int jt = 0; jt < 4; ++jt) {
      bf16x8 b0 = bfrag_w(W, 0, jt * 16, lane15, quad);
      bf16x8 b1 = bfrag_w(W, 32, jt * 16, lane15, quad);
      f32x4 z = {0.f, 0.f, 0.f, 0.f};
      z = __builtin_amdgcn_mfma_f32_16x16x32_bf16(A0, b0, z, 0, 0, 0);
      z = __builtin_amdgcn_mfma_f32_16x16x32_bf16(A1, b1, z, 0, 0, 0);
#pragma unroll
      for (int i = 0; i < 4; ++i) {
        int r = m0 + quad * 4 + i;
        if (r < NN) Adst[(size_t)r * HD + jt * 16 + lane15] = f2bf(z[i]);
      }
    }
  }
  // ---- h_out: exact f32 pass
  {
    int r = t >> 2, p = t & 3;
    int gr = n0 + r;
    int grc = gr < NN ? gr : NN - 1;
    const float* rp = ht + (size_t)grc * HD + p * 16;
    float4 v0 = *(const float4*)(rp + 0);
    float4 v1 = *(const float4*)(rp + 4);
    float4 v2 = *(const float4*)(rp + 8);
    float4 v3 = *(const float4*)(rp + 12);
    float ssq = v0.x*v0.x + v0.y*v0.y + v0.z*v0.z + v0.w*v0.w
              + v1.x*v1.x + v1.y*v1.y + v1.z*v1.z + v1.w*v1.w
              + v2.x*v2.x + v2.y*v2.y + v2.z*v2.z + v2.w*v2.w
              + v3.x*v3.x + v3.y*v3.y + v3.z*v3.z + v3.w*v3.w;
    ssq += __shfl_xor(ssq, 1, 64);
    ssq += __shfl_xor(ssq, 2, 64);
    float nu = fmaxf(sqrtf(ssq), 1e-15f);
    float hs = tanhf(nu) / nu;
    if (gr < NN) {
      float* op = h_out + (size_t)gr * HD + p * 16;
      *(float4*)(op + 0)  = make_float4(v0.x*hs, v0.y*hs, v0.z*hs, v0.w*hs);
      *(float4*)(op + 4)  = make_float4(v1.x*hs, v1.y*hs, v1.z*hs, v1.w*hs);
      *(float4*)(op + 8)  = make_float4(v2.x*hs, v2.y*hs, v2.z*hs, v2.w*hs);
      *(float4*)(op + 12) = make_float4(v3.x*hs, v3.y*hs, v3.z*hs, v3.w*hs);
    }
  }
}

// ---------------------------------------------------------------- edge scores (8 lanes/edge, 8 edges/wave)
__global__ void __launch_bounds__(256) k_edge(const int* __restrict__ src,
                                              const int* __restrict__ dst,
                                              const int* __restrict__ etype,
                                              const ushort* __restrict__ Asrc,
                                              const ushort* __restrict__ Adst,
                                              const float* __restrict__ Te2,
                                              const float* __restrict__ Wes2,
                                              const float* __restrict__ bes2,
                                              float* __restrict__ edge_scores) {
  int t = threadIdx.x;
  int lane = t & 63;
  int lq = lane & 7, lg = lane >> 3;
  int w = (blockIdx.x * 256 + t) >> 6;
  int e = w * 8 + lg;
  float p = 0.f;
  if (e < NE) {
    int si = src[e], di = dst[e], ti = etype[e];
    uint4 av = *(const uint4*)&Asrc[(size_t)si * HD + lq * 8];
    uint4 bv = *(const uint4*)&Adst[(size_t)di * HD + lq * 8];
    const float* tp = &Te2[ti * HD + lq * 8];
    float4 t0 = *(const float4*)tp;
    float4 t1 = *(const float4*)(tp + 4);
    const float* wp = &Wes2[lq * 8];
    float4 w0 = *(const float4*)wp;
    float4 w1 = *(const float4*)(wp + 4);
    p += fmaxf(bflo(av.x) + bflo(bv.x) + t0.x, 0.f) * w0.x;
    p += fmaxf(bfhi(av.x) + bfhi(bv.x) + t0.y, 0.f) * w0.y;
    p += fmaxf(bflo(av.y) + bflo(bv.y) + t0.z, 0.f) * w0.z;
    p += fmaxf(bfhi(av.y) + bfhi(bv.y) + t0.w, 0.f) * w0.w;
    p += fmaxf(bflo(av.z) + bflo(bv.z) + t1.x, 0.f) * w1.x;
    p += fmaxf(bfhi(av.z) + bfhi(bv.z) + t1.y, 0.f) * w1.y;
    p += fmaxf(bflo(av.w) + bflo(bv.w) + t1.z, 0.f) * w1.z;
    p += fmaxf(bfhi(av.w) + bfhi(bv.w) + t1.w, 0.f) * w1.w;
  }
  p += __shfl_xor(p, 1, 64);
  p += __shfl_xor(p, 2, 64);
  p += __shfl_xor(p, 4, 64);
  if (e < NE && lq == 0) edge_scores[e] = 1.f / (1.f + __expf(-(p + bes2[0])));
}

// ---------------------------------------------------------------- launch
extern "C" void kernel_launch(void* const* d_in, const int* in_sizes, int n_in,
                              void* d_out, int out_size, void* d_ws, size_t ws_size,
                              hipStream_t stream) {
  const float* node_features = (const float*)d_in[0];
  const float* edge_desc = (const float*)d_in[1];
  const float* query = (const float*)d_in[2];
  const float* Wn = (const float*)d_in[3];
  const float* bn = (const float*)d_in[4];
  const float* ts = (const float*)d_in[5];
  const float* Wq = (const float*)d_in[6];
  const float* bq = (const float*)d_in[7];
  const float* Ws_ = (const float*)d_in[8];
  const float* bs = (const float*)d_in[9];
  const float* attn_a = (const float*)d_in[10];
  const float* Wmp = (const float*)d_in[11];
  const float* bmp = (const float*)d_in[12];
  const float* Wns1 = (const float*)d_in[13];
  const float* bns1 = (const float*)d_in[14];
  const float* Wns2 = (const float*)d_in[15];
  const float* bns2 = (const float*)d_in[16];
  const float* Wes1 = (const float*)d_in[17];
  const float* bes1 = (const float*)d_in[18];
  const float* Wes2 = (const float*)d_in[19];
  const float* bes2 = (const float*)d_in[20];
  const int* edge_index = (const int*)d_in[21];
  const int* etype = (const int*)d_in[22];
  const int* src = edge_index;
  const int* dst = edge_index + NE;

  float* out_ns = (float*)d_out;
  float* out_es = out_ns + NN;
  float* out_h = out_es + NE;
  float* out_te = out_h + (size_t)NN * HD;

  char* w = (char*)d_ws;
  auto alloc = [&](size_t bytes) {
    char* p = w;
    w += (bytes + 1023) & ~(size_t)1023;
    return p;
  };
  float* ht_a = (float*)alloc((size_t)NN * HD * 4);
  float* ht_b = (float*)alloc((size_t)NN * HD * 4);
  ushort* msgbf = (ushort*)alloc((size_t)NN * HD * 2);
  ushort* Asrc = (ushort*)alloc((size_t)NN * HD * 2);
  ushort* Adst = (ushort*)alloc((size_t)NN * HD * 2);
  float* p_src = (float*)alloc(NN * 4);
  float* p_dst = (float*)alloc(NN * 4);
  float* s_buf = (float*)alloc(NE * 4);
  float* qb = (float*)alloc(HD * 4);
  float* qe = (float*)alloc(HD * 4);
  float* ta3 = (float*)alloc(NLAY * NTT * 4);
  float* Te2 = (float*)alloc(NTT * HD * 4);
  int* cnt = (int*)alloc(NN * 4);
  int* row_ptr = (int*)alloc((NN + 1) * 4);
  int* cursor = (int*)alloc(NN * 4);
  int* bsum = (int*)alloc(NCHUNK * 4);
  int* boff = (int*)alloc(NCHUNK * 4);
  int* bucket_cursor = (int*)alloc(NBUCK * 4);
  uint* csr = (uint*)alloc(NE * 4);
  // ebuf (NE x 8B = 6.4 MB) aliases Asrc+Adst (12.8 MB): CSR build finishes
  // before k_score ever writes Asrc/Adst. No overlap in stream order.
  uint2* ebuf = (uint2*)Asrc;

  hipMemsetAsync(cnt, 0, NN * 4, stream);
  k_setup<<<1, 256, 0, stream>>>(edge_desc, query, Wq, bq, Ws_, bs, attn_a, Wns1, bns1,
                                 Wes1, bes1, out_te, qb, ta3, qe);
  k_te2<<<16, 256, 0, stream>>>(out_te, qe, Wes1, Te2);
  k_hist<<<NE / 256, 256, 0, stream>>>(dst, cnt);
  k_scanA<<<NCHUNK, 256, 0, stream>>>(cnt, bsum);
  k_scanB<<<1, 64, 0, stream>>>(bsum, boff, row_ptr);
  k_scanC<<<NCHUNK, 256, 0, stream>>>(cnt, boff, row_ptr, cursor);
  k_binit<<<1, 256, 0, stream>>>(row_ptr, bucket_cursor);
  k_bin<<<NBINBLK, 256, 0, stream>>>(src, dst, etype, bucket_cursor, ebuf);
  k_scatter2<<<NBUCK, 256, 0, stream>>>(row_ptr, ebuf, cursor, csr);
  k_proj<<<(NN + 63) / 64, 256, 0, stream>>>(node_features, Wn, bn, ts, ht_a);

  float* cur = ht_a;
  float* nxt = ht_b;
  for (int l = 0; l < NLAY; ++l) {
    k_msg<<<(NN + 63) / 64, 256, 0, stream>>>(cur, Wmp + l * HD * HD, bmp + l * HD,
                                              attn_a + l * (2 * HD + TDD), msgbf, p_src, p_dst);
    k_agg<<<(NN + 3) / 4, 256, 0, stream>>>(row_ptr, csr, p_src, p_dst, ta3 + l * NTT,
                                            msgbf, nxt, s_buf);
    float* tmp = cur; cur = nxt; nxt = tmp;
  }
  k_score<<<(NN + 63) / 64, 256, 0, stream>>>(cur, Wns1, qb, Wns2, bns2, Wes1,
                                              out_ns, out_h, Asrc, Adst);
  k_edge<<<(NE + 31) / 32, 256, 0, stream>>>(src, dst, etype, Asrc, Adst, Te2,
                                             Wes2, bes2, out_es);
}

// Round 8
// 411.671 us; speedup vs baseline: 1.3614x; 1.0491x over previous
//
#include <hip/hip_runtime.h>
#include <math.h>

#define NN 50000
#define NE 800000
#define NFD 256
#define HD 64
#define QDD 128
#define TDD 32
#define NTT 64
#define NLAY 3
#define LCLAMP 6.1030340f   // atanh(1 - 1e-5)
#define CHUNK 1024
#define NCHUNK 49           // ceil(50000/1024)
#define NBUCK 196           // ceil(50000/256) coarse buckets (dst >> 8)
#define EPB 2048            // edges per k_bin block
#define NBINBLK 391         // ceil(800000/2048)
#define PST 72              // k_proj LDS tile stride in shorts (phase-conflict-free)

typedef unsigned int uint;
typedef unsigned short ushort;
typedef __attribute__((ext_vector_type(8))) short bf16x8;
typedef __attribute__((ext_vector_type(4))) float f32x4;

__device__ __forceinline__ ushort f2bf(float f) {
  uint u = __float_as_uint(f);
  uint r = (u + 0x7FFFu + ((u >> 16) & 1u)) >> 16;
  return (ushort)r;
}
__device__ __forceinline__ short f2bfs(float f) { return (short)f2bf(f); }
__device__ __forceinline__ float bf2f(short s) { return __uint_as_float(((uint)(ushort)s) << 16); }
__device__ __forceinline__ float bflo(uint w) { return __uint_as_float(w << 16); }
__device__ __forceinline__ float bfhi(uint w) { return __uint_as_float(w & 0xFFFF0000u); }

// A-frag from 8 consecutive f32 (row-major activation row)
__device__ __forceinline__ bf16x8 frag_f32(const float* p) {
  float4 a = *(const float4*)p;
  float4 b = *(const float4*)(p + 4);
  bf16x8 r;
  r[0] = f2bfs(a.x); r[1] = f2bfs(a.y); r[2] = f2bfs(a.z); r[3] = f2bfs(a.w);
  r[4] = f2bfs(b.x); r[5] = f2bfs(b.y); r[6] = f2bfs(b.z); r[7] = f2bfs(b.w);
  return r;
}
// B-frag from row-major W[K][64]: k=k0+quad*8+j, n=j0+lane15
__device__ __forceinline__ bf16x8 bfrag_w(const float* W, int k0, int j0, int lane15, int quad) {
  bf16x8 r;
#pragma unroll
  for (int j = 0; j < 8; ++j) r[j] = f2bfs(W[(k0 + quad * 8 + j) * HD + j0 + lane15]);
  return r;
}

// ---------------------------------------------------------------- setup (small dense precomputes)
__global__ void k_setup(const float* __restrict__ edge_desc, const float* __restrict__ query,
                        const float* __restrict__ Wq, const float* __restrict__ bq,
                        const float* __restrict__ Ws, const float* __restrict__ bs,
                        const float* __restrict__ attn_a,
                        const float* __restrict__ Wns1, const float* __restrict__ bns1,
                        const float* __restrict__ Wes1, const float* __restrict__ bes1,
                        float* __restrict__ out_type_emb,
                        float* __restrict__ qb, float* __restrict__ ta3,
                        float* __restrict__ qe) {
  __shared__ float te_l[NTT * TDD];
  __shared__ float q_l[HD];
  int t = threadIdx.x;
  if (t < HD) {
    float acc = bq[t];
    for (int k = 0; k < QDD; ++k) acc += query[k] * Wq[k * HD + t];
    q_l[t] = acc;
  }
  for (int idx = t; idx < NTT * TDD; idx += 256) {
    int ty = idx / TDD, d = idx % TDD;
    float acc = bs[d];
    for (int k = 0; k < 64; ++k) acc += edge_desc[ty * 64 + k] * Ws[k * TDD + d];
    float v = tanhf(acc);
    te_l[idx] = v;
    out_type_emb[idx] = v;
  }
  __syncthreads();
  if (t < NLAY * NTT) {
    int l = t / NTT, ty = t % NTT;
    float acc = 0.f;
    for (int d = 0; d < TDD; ++d) acc += te_l[ty * TDD + d] * attn_a[l * (2 * HD + TDD) + 2 * HD + d];
    ta3[t] = acc;
  }
  if (t < HD) {
    float a1 = bns1[t], a2 = bes1[t];
    for (int k = 0; k < HD; ++k) {
      a1 += q_l[k] * Wns1[(HD + k) * HD + t];
      a2 += q_l[k] * Wes1[(2 * HD + TDD + k) * HD + t];
    }
    qb[t] = a1;
    qe[t] = a2;
  }
}

// Te2[ty][j] = type_emb[ty] @ Wes1[te-part] + qe (bias folded); 16 blocks x 256
__global__ void k_te2(const float* __restrict__ te, const float* __restrict__ qe,
                      const float* __restrict__ Wes1, float* __restrict__ Te2) {
  int idx = blockIdx.x * 256 + threadIdx.x;   // 4096 total
  int ty = idx >> 6, j = idx & 63;
  float acc = qe[j];
#pragma unroll
  for (int d = 0; d < TDD; ++d) acc += te[ty * TDD + d] * Wes1[(2 * HD + d) * HD + j];
  Te2[idx] = acc;
}

// ---------------------------------------------------------------- CSR build
__global__ void k_hist(const int* __restrict__ dst, int* __restrict__ cnt) {
  int e = blockIdx.x * 256 + threadIdx.x;
  if (e < NE) atomicAdd(&cnt[dst[e]], 1);
}

__global__ void k_scanA(const int* __restrict__ cnt, int* __restrict__ bsum) {
  __shared__ int ws[4];
  int t = threadIdx.x;
  int c0 = blockIdx.x * CHUNK;
  int s = 0;
#pragma unroll
  for (int it = 0; it < 4; ++it) {
    int i = c0 + it * 256 + t;
    if (i < NN) s += cnt[i];
  }
#pragma unroll
  for (int off = 1; off < 64; off <<= 1) s += __shfl_xor(s, off, 64);
  if ((t & 63) == 0) ws[t >> 6] = s;
  __syncthreads();
  if (t == 0) bsum[blockIdx.x] = ws[0] + ws[1] + ws[2] + ws[3];
}

__global__ void k_scanB(const int* __restrict__ bsum, int* __restrict__ boff,
                        int* __restrict__ row_ptr) {
  int t = threadIdx.x;  // 64 threads
  int v = (t < NCHUNK) ? bsum[t] : 0;
  int x = v;
#pragma unroll
  for (int off = 1; off < 64; off <<= 1) {
    int y = __shfl_up(x, off, 64);
    if (t >= off) x += y;
  }
  if (t < NCHUNK) boff[t] = x - v;
  if (t == 63) row_ptr[NN] = x;
}

__global__ void k_scanC(const int* __restrict__ cnt, const int* __restrict__ boff,
                        int* __restrict__ row_ptr, int* __restrict__ cursor) {
  __shared__ int wsum[4], woff_s[4];
  int t = threadIdx.x;
  int c0 = blockIdx.x * CHUNK;
  int i0 = c0 + t * 4;
  int v0 = (i0 + 0 < NN) ? cnt[i0 + 0] : 0;
  int v1 = (i0 + 1 < NN) ? cnt[i0 + 1] : 0;
  int v2 = (i0 + 2 < NN) ? cnt[i0 + 2] : 0;
  int v3 = (i0 + 3 < NN) ? cnt[i0 + 3] : 0;
  int s4 = v0 + v1 + v2 + v3;
  int lane = t & 63, wid = t >> 6;
  int x = s4;
#pragma unroll
  for (int off = 1; off < 64; off <<= 1) {
    int y = __shfl_up(x, off, 64);
    if (lane >= off) x += y;
  }
  if (lane == 63) wsum[wid] = x;
  __syncthreads();
  if (t == 0) {
    int a = 0;
    for (int i = 0; i < 4; ++i) { woff_s[i] = a; a += wsum[i]; }
  }
  __syncthreads();
  int base = boff[blockIdx.x] + woff_s[wid] + (x - s4);
  int r0 = base, r1 = base + v0, r2 = r1 + v1, r3 = r2 + v2;
  if (i0 + 0 < NN) { row_ptr[i0 + 0] = r0; cursor[i0 + 0] = r0; }
  if (i0 + 1 < NN) { row_ptr[i0 + 1] = r1; cursor[i0 + 1] = r1; }
  if (i0 + 2 < NN) { row_ptr[i0 + 2] = r2; cursor[i0 + 2] = r2; }
  if (i0 + 3 < NN) { row_ptr[i0 + 3] = r3; cursor[i0 + 3] = r3; }
}

// bucket_cursor[b] = row_ptr[b*256]
__global__ void k_binit(const int* __restrict__ row_ptr, int* __restrict__ bucket_cursor) {
  int b = blockIdx.x * 256 + threadIdx.x;
  if (b < NBUCK) bucket_cursor[b] = row_ptr[b << 8];
}

// phase B: bin edges by coarse bucket (dst>>8) into ebuf (same layout as csr)
__global__ void __launch_bounds__(256) k_bin(const int* __restrict__ src,
                                             const int* __restrict__ dst,
                                             const int* __restrict__ etype,
                                             int* __restrict__ bucket_cursor,
                                             uint2* __restrict__ ebuf) {
  __shared__ int cntl[NBUCK];
  __shared__ int gbase[NBUCK];
  int t = threadIdx.x;
  for (int i = t; i < NBUCK; i += 256) cntl[i] = 0;
  __syncthreads();
  int e0 = blockIdx.x * EPB;
  int dd[8], pk[8], rk[8], bk[8];
#pragma unroll
  for (int i = 0; i < 8; ++i) {
    int e = e0 + t + i * 256;
    if (e < NE) {
      int d = dst[e];
      dd[i] = d;
      pk[i] = src[e] | (etype[e] << 16);
      bk[i] = d >> 8;
      rk[i] = atomicAdd(&cntl[bk[i]], 1);
    } else dd[i] = -1;
  }
  __syncthreads();
  if (t < NBUCK && cntl[t] > 0) gbase[t] = atomicAdd(&bucket_cursor[t], cntl[t]);
  __syncthreads();
#pragma unroll
  for (int i = 0; i < 8; ++i) {
    if (dd[i] >= 0) {
      int pos = gbase[bk[i]] + rk[i];
      ebuf[pos] = make_uint2((uint)pk[i], (uint)dd[i]);
    }
  }
}

// phase C: per-bucket scatter to final CSR position (writes L2-local, 16KB window)
__global__ void __launch_bounds__(256) k_scatter2(const int* __restrict__ row_ptr,
                                                  const uint2* __restrict__ ebuf,
                                                  int* __restrict__ cursor,
                                                  uint* __restrict__ csr) {
  int b = blockIdx.x;
  int n0 = b << 8;
  int n1 = n0 + 256; if (n1 > NN) n1 = NN;
  int lo = row_ptr[n0];
  int hi = row_ptr[n1];
  for (int i = lo + threadIdx.x; i < hi; i += 256) {
    uint2 r = ebuf[i];
    int pos = atomicAdd(&cursor[(int)r.y], 1);
    csr[pos] = r.x;
  }
}

// ---------------------------------------------------------------- initial projection (MFMA, pipelined LDS staging)
// ht0 = clamp_norm((X @ Wn + bn) * ts). Block = 64 nodes; X streamed in 64x64 f32
// chunks: coalesced float4 loads -> bf16 convert -> double-buffered LDS (stride 72
// shorts: staging writes, A-frag ds_read_b128 both phase-conflict-free). Prefetch of
// chunk c+1 is in flight during MFMA(c).
__global__ void __launch_bounds__(256) k_proj(const float* __restrict__ X,
                                              const float* __restrict__ Wn,
                                              const float* __restrict__ bn,
                                              const float* __restrict__ ts_p,
                                              float* __restrict__ ht0) {
  __shared__ ushort buf[2][64 * PST];            // 2 x 9216 B
  float* st = (float*)&buf[0][0];                // epilogue alias: 64 x 72 f32 (18432 B)
  int t = threadIdx.x;
  int lane = t & 63, wv = t >> 6;
  int lane15 = lane & 15, quad = lane >> 4;
  int n0 = blockIdx.x * 64;
  int j0 = wv * 16;
  bf16x8 B[8];
#pragma unroll
  for (int fb = 0; fb < 8; ++fb) B[fb] = bfrag_w(Wn, fb * 32, j0, lane15, quad);

  int srow = t >> 2;              // staging row 0..63
  int scg = (t & 3) * 16;         // staging col group
  int grow = n0 + srow; if (grow >= NN) grow = NN - 1;
  const float* xrow = X + (size_t)grow * NFD + scg;

  f32x4 acc[4];
#pragma unroll
  for (int mt = 0; mt < 4; ++mt) acc[mt] = (f32x4){0.f, 0.f, 0.f, 0.f};

  // prefetch chunk 0 (coalesced: 4 lanes cover 256B of one row)
  float4 r0 = *(const float4*)(xrow + 0);
  float4 r1 = *(const float4*)(xrow + 4);
  float4 r2 = *(const float4*)(xrow + 8);
  float4 r3 = *(const float4*)(xrow + 12);

  for (int c = 0; c < 4; ++c) {
    // convert + write chunk c to buf[c&1]
    ushort* wp = &buf[c & 1][srow * PST + scg];
    uint4 o0, o1;
    o0.x = (uint)f2bf(r0.x) | ((uint)f2bf(r0.y) << 16);
    o0.y = (uint)f2bf(r0.z) | ((uint)f2bf(r0.w) << 16);
    o0.z = (uint)f2bf(r1.x) | ((uint)f2bf(r1.y) << 16);
    o0.w = (uint)f2bf(r1.z) | ((uint)f2bf(r1.w) << 16);
    o1.x = (uint)f2bf(r2.x) | ((uint)f2bf(r2.y) << 16);
    o1.y = (uint)f2bf(r2.z) | ((uint)f2bf(r2.w) << 16);
    o1.z = (uint)f2bf(r3.x) | ((uint)f2bf(r3.y) << 16);
    o1.w = (uint)f2bf(r3.z) | ((uint)f2bf(r3.w) << 16);
    *(uint4*)wp = o0;
    *(uint4*)(wp + 8) = o1;
    if (c < 3) {
      const float* nx = xrow + (c + 1) * 64;
      r0 = *(const float4*)(nx + 0);
      r1 = *(const float4*)(nx + 4);
      r2 = *(const float4*)(nx + 8);
      r3 = *(const float4*)(nx + 12);
    }
    __syncthreads();
    const ushort* bp = &buf[c & 1][0];
#pragma unroll
    for (int mt = 0; mt < 4; ++mt) {
#pragma unroll
      for (int ks = 0; ks < 2; ++ks) {
        bf16x8 A = *(const bf16x8*)&bp[(mt * 16 + lane15) * PST + ks * 32 + quad * 8];
        acc[mt] = __builtin_amdgcn_mfma_f32_16x16x32_bf16(A, B[c * 2 + ks], acc[mt], 0, 0, 0);
      }
    }
    // no trailing sync needed: next write targets the other buffer; barrier at
    // iteration c+1 orders reuse (see analysis).
  }
  __syncthreads();
  // epilogue: deposit (acc+bn)*ts into f32 st[64][72], norm-clamp, coalesced store
  float ts = ts_p[0];
  float vb = bn[j0 + lane15];
#pragma unroll
  for (int mt = 0; mt < 4; ++mt)
#pragma unroll
    for (int i = 0; i < 4; ++i)
      st[(mt * 16 + quad * 4 + i) * PST + j0 + lane15] = (acc[mt][i] + vb) * ts;
  __syncthreads();
  int r = t >> 2, p = t & 3;
  const float* rp = &st[r * PST + p * 16];
  float4 v0 = *(const float4*)(rp + 0);
  float4 v1 = *(const float4*)(rp + 4);
  float4 v2 = *(const float4*)(rp + 8);
  float4 v3 = *(const float4*)(rp + 12);
  float ssq = v0.x*v0.x + v0.y*v0.y + v0.z*v0.z + v0.w*v0.w
            + v1.x*v1.x + v1.y*v1.y + v1.z*v1.z + v1.w*v1.w
            + v2.x*v2.x + v2.y*v2.y + v2.z*v2.z + v2.w*v2.w
            + v3.x*v3.x + v3.y*v3.y + v3.z*v3.z + v3.w*v3.w;
  ssq += __shfl_xor(ssq, 1, 64);
  ssq += __shfl_xor(ssq, 2, 64);
  float nu = fmaxf(sqrtf(ssq), 1e-15f);
  float sc = fminf(nu, LCLAMP) / nu;
  int orow = n0 + r;
  if (orow < NN) {
    float* op = &ht0[(size_t)orow * HD + p * 16];
    *(float4*)(op + 0)  = make_float4(v0.x*sc, v0.y*sc, v0.z*sc, v0.w*sc);
    *(float4*)(op + 4)  = make_float4(v1.x*sc, v1.y*sc, v1.z*sc, v1.w*sc);
    *(float4*)(op + 8)  = make_float4(v2.x*sc, v2.y*sc, v2.z*sc, v2.w*sc);
    *(float4*)(op + 12) = make_float4(v3.x*sc, v3.y*sc, v3.z*sc, v3.w*sc);
  }
}

// ---------------------------------------------------------------- msg = ht @ Wmp + bmp (bf16); p_src/p_dst (MFMA)
__global__ void __launch_bounds__(256) k_msg(const float* __restrict__ ht,
                                             const float* __restrict__ Wmp_l,
                                             const float* __restrict__ bmp_l,
                                             const float* __restrict__ attn_l,
                                             ushort* __restrict__ msgbf,
                                             float* __restrict__ p_src,
                                             float* __restrict__ p_dst) {
  int t = threadIdx.x;
  int lane = t & 63, wv = t >> 6;
  int lane15 = lane & 15, quad = lane >> 4;
  int m0 = blockIdx.x * 64 + wv * 16;
  bf16x8 B[4][2];
  float vb[4];
#pragma unroll
  for (int jt = 0; jt < 4; ++jt) {
    B[jt][0] = bfrag_w(Wmp_l, 0, jt * 16, lane15, quad);
    B[jt][1] = bfrag_w(Wmp_l, 32, jt * 16, lane15, quad);
    vb[jt] = bmp_l[jt * 16 + lane15];
  }
  int row = m0 + lane15;
  int rowc = row < NN ? row : NN - 1;
  bf16x8 A0 = frag_f32(ht + (size_t)rowc * HD + quad * 8);
  bf16x8 A1 = frag_f32(ht + (size_t)rowc * HD + 32 + quad * 8);
  f32x4 acc[4];
#pragma unroll
  for (int jt = 0; jt < 4; ++jt) {
    f32x4 z = {0.f, 0.f, 0.f, 0.f};
    z = __builtin_amdgcn_mfma_f32_16x16x32_bf16(A0, B[jt][0], z, 0, 0, 0);
    z = __builtin_amdgcn_mfma_f32_16x16x32_bf16(A1, B[jt][1], z, 0, 0, 0);
    acc[jt] = z;
  }
#pragma unroll
  for (int jt = 0; jt < 4; ++jt)
#pragma unroll
    for (int i = 0; i < 4; ++i) {
      int r = m0 + quad * 4 + i;
      if (r < NN) msgbf[(size_t)r * HD + jt * 16 + lane15] = f2bf(acc[jt][i] + vb[jt]);
    }
  float4 a1l = *(const float4*)&attn_l[quad * 8];
  float4 a1h = *(const float4*)&attn_l[quad * 8 + 4];
  float4 a1l2 = *(const float4*)&attn_l[32 + quad * 8];
  float4 a1h2 = *(const float4*)&attn_l[32 + quad * 8 + 4];
  float4 a2l = *(const float4*)&attn_l[64 + quad * 8];
  float4 a2h = *(const float4*)&attn_l[64 + quad * 8 + 4];
  float4 a2l2 = *(const float4*)&attn_l[96 + quad * 8];
  float4 a2h2 = *(const float4*)&attn_l[96 + quad * 8 + 4];
  float p1 = bf2f(A0[0])*a1l.x + bf2f(A0[1])*a1l.y + bf2f(A0[2])*a1l.z + bf2f(A0[3])*a1l.w
           + bf2f(A0[4])*a1h.x + bf2f(A0[5])*a1h.y + bf2f(A0[6])*a1h.z + bf2f(A0[7])*a1h.w
           + bf2f(A1[0])*a1l2.x + bf2f(A1[1])*a1l2.y + bf2f(A1[2])*a1l2.z + bf2f(A1[3])*a1l2.w
           + bf2f(A1[4])*a1h2.x + bf2f(A1[5])*a1h2.y + bf2f(A1[6])*a1h2.z + bf2f(A1[7])*a1h2.w;
  float p2 = bf2f(A0[0])*a2l.x + bf2f(A0[1])*a2l.y + bf2f(A0[2])*a2l.z + bf2f(A0[3])*a2l.w
           + bf2f(A0[4])*a2h.x + bf2f(A0[5])*a2h.y + bf2f(A0[6])*a2h.z + bf2f(A0[7])*a2h.w
           + bf2f(A1[0])*a2l2.x + bf2f(A1[1])*a2l2.y + bf2f(A1[2])*a2l2.z + bf2f(A1[3])*a2l2.w
           + bf2f(A1[4])*a2h2.x + bf2f(A1[5])*a2h2.y + bf2f(A1[6])*a2h2.z + bf2f(A1[7])*a2h2.w;
  p1 += __shfl_xor(p1, 16, 64); p1 += __shfl_xor(p1, 32, 64);
  p2 += __shfl_xor(p2, 16, 64); p2 += __shfl_xor(p2, 32, 64);
  if (quad == 0 && row < NN) { p_src[row] = p1; p_dst[row] = p2; }
}

// ---------------------------------------------------------------- softmax-aggregate (wave/node, 8-wide gather)
__global__ void __launch_bounds__(256) k_agg(const int* __restrict__ row_ptr,
                                             const uint* __restrict__ csr,
                                             const float* __restrict__ p_src,
                                             const float* __restrict__ p_dst,
                                             const float* __restrict__ ta_l,
                                             const ushort* __restrict__ msgbf,
                                             float* __restrict__ ht_out,
                                             float* __restrict__ s_buf) {
  int lane = threadIdx.x & 63;
  int n = (blockIdx.x * 256 + threadIdx.x) >> 6;
  if (n >= NN) return;
  int start = row_ptr[n], end = row_ptr[n + 1];
  int deg = end - start;
  float pd = p_dst[n];
  int lq = lane & 7, lg = lane >> 3;
  float acc[8];
#pragma unroll
  for (int u = 0; u < 8; ++u) acc[u] = 0.f;
  float exsum = 0.f;

  if (deg <= 64) {
    bool valid = lane < deg;
    float s = -3.4e38f;
    int sidx = 0;
    if (valid) {
      uint pk = csr[start + lane];
      sidx = (int)(pk & 0xFFFFu);
      int ty = (int)(pk >> 16);
      float v = p_src[sidx] + pd + ta_l[ty];
      s = (v > 0.f) ? v : 0.2f * v;
    }
    float m = s;
#pragma unroll
    for (int off = 32; off >= 1; off >>= 1) m = fmaxf(m, __shfl_xor(m, off, 64));
    float ex = valid ? __expf(s - m) : 0.f;
    exsum = ex;
    for (int it = 0; it < deg; it += 8) {
      int el = it + lg;
      float exk = __shfl(ex, el, 64);
      int sk = __shfl(sidx, el, 64);
      if (el < deg) {
        uint4 mv = *(const uint4*)&msgbf[(size_t)sk * HD + lq * 8];
        acc[0] += exk * bflo(mv.x); acc[1] += exk * bfhi(mv.x);
        acc[2] += exk * bflo(mv.y); acc[3] += exk * bfhi(mv.y);
        acc[4] += exk * bflo(mv.z); acc[5] += exk * bfhi(mv.z);
        acc[6] += exk * bflo(mv.w); acc[7] += exk * bfhi(mv.w);
      }
    }
  } else {
    float m = -3.4e38f;
    for (int base = start; base < end; base += 64) {
      int i = base + lane;
      float s = -3.4e38f;
      if (i < end) {
        uint pk = csr[i];
        int sidx = (int)(pk & 0xFFFFu);
        int ty = (int)(pk >> 16);
        float v = p_src[sidx] + pd + ta_l[ty];
        s = (v > 0.f) ? v : 0.2f * v;
        s_buf[i] = s;
      }
      m = fmaxf(m, s);
    }
#pragma unroll
    for (int off = 32; off >= 1; off >>= 1) m = fmaxf(m, __shfl_xor(m, off, 64));
    for (int base = start; base < end; base += 64) {
      int i = base + lane;
      if (i < end) {
        float ex = __expf(s_buf[i] - m);
        s_buf[i] = ex;
        exsum += ex;
      }
    }
    for (int it = start; it < end; it += 8) {
      int el = it + lg;
      if (el < end) {
        float exk = s_buf[el];
        int sk = (int)(csr[el] & 0xFFFFu);
        uint4 mv = *(const uint4*)&msgbf[(size_t)sk * HD + lq * 8];
        acc[0] += exk * bflo(mv.x); acc[1] += exk * bfhi(mv.x);
        acc[2] += exk * bflo(mv.y); acc[3] += exk * bfhi(mv.y);
        acc[4] += exk * bflo(mv.z); acc[5] += exk * bfhi(mv.z);
        acc[6] += exk * bflo(mv.w); acc[7] += exk * bfhi(mv.w);
      }
    }
  }
#pragma unroll
  for (int u = 0; u < 8; ++u) {
    acc[u] += __shfl_xor(acc[u], 8, 64);
    acc[u] += __shfl_xor(acc[u], 16, 64);
    acc[u] += __shfl_xor(acc[u], 32, 64);
  }
#pragma unroll
  for (int off = 32; off >= 1; off >>= 1) exsum += __shfl_xor(exsum, off, 64);
  float inv = 1.f / (exsum + 1e-15f);
  float ss = 0.f;
#pragma unroll
  for (int u = 0; u < 8; ++u) {
    float v = fmaxf(acc[u] * inv, 0.f);
    acc[u] = v;
    ss += v * v;
  }
  ss += __shfl_xor(ss, 1, 64);
  ss += __shfl_xor(ss, 2, 64);
  ss += __shfl_xor(ss, 4, 64);
  float nu = fmaxf(sqrtf(ss), 1e-15f);
  float sc = fminf(nu, LCLAMP) / nu;
  if (lane < 8) {
    *(float4*)&ht_out[(size_t)n * HD + lane * 8] =
        make_float4(acc[0] * sc, acc[1] * sc, acc[2] * sc, acc[3] * sc);
    *(float4*)&ht_out[(size_t)n * HD + lane * 8 + 4] =
        make_float4(acc[4] * sc, acc[5] * sc, acc[6] * sc, acc[7] * sc);
  }
}

// ---------------------------------------------------------------- heads (MFMA): node score, Asrc/Adst, h_out
__global__ void __launch_bounds__(256) k_score(const float* __restrict__ ht,
                                               const float* __restrict__ Wns1,
                                               const float* __restrict__ qb,
                                               const float* __restrict__ Wns2,
                                               const float* __restrict__ bns2,
                                               const float* __restrict__ Wes1,
                                               float* __restrict__ node_scores,
                                               float* __restrict__ h_out,
                                               ushort* __restrict__ Asrc,
                                               ushort* __restrict__ Adst) {
  int t = threadIdx.x;
  int lane = t & 63, wv = t >> 6;
  int lane15 = lane & 15, quad = lane >> 4;
  int n0 = blockIdx.x * 64;
  int m0 = n0 + wv * 16;
  int row = m0 + lane15;
  int rowc = row < NN ? row : NN - 1;
  bf16x8 A0 = frag_f32(ht + (size_t)rowc * HD + quad * 8);
  bf16x8 A1 = frag_f32(ht + (size_t)rowc * HD + 32 + quad * 8);

  // ---- node head
  {
    f32x4 acc[4];
#pragma unroll
    for (int jt = 0; jt < 4; ++jt) {
      bf16x8 b0 = bfrag_w(Wns1, 0, jt * 16, lane15, quad);
      bf16x8 b1 = bfrag_w(Wns1, 32, jt * 16, lane15, quad);
      f32x4 z = {0.f, 0.f, 0.f, 0.f};
      z = __builtin_amdgcn_mfma_f32_16x16x32_bf16(A0, b0, z, 0, 0, 0);
      z = __builtin_amdgcn_mfma_f32_16x16x32_bf16(A1, b1, z, 0, 0, 0);
      acc[jt] = z;
    }
    float vqb[4], vw2[4];
#pragma unroll
    for (int jt = 0; jt < 4; ++jt) { vqb[jt] = qb[jt * 16 + lane15]; vw2[jt] = Wns2[jt * 16 + lane15]; }
    float b2 = bns2[0];
#pragma unroll
    for (int i = 0; i < 4; ++i) {
      float si = 0.f;
#pragma unroll
      for (int jt = 0; jt < 4; ++jt) si += fmaxf(acc[jt][i] + vqb[jt], 0.f) * vw2[jt];
      si += __shfl_xor(si, 1, 64);
      si += __shfl_xor(si, 2, 64);
      si += __shfl_xor(si, 4, 64);
      si += __shfl_xor(si, 8, 64);
      int r = m0 + quad * 4 + i;
      if (lane15 == 0 && r < NN) node_scores[r] = 1.f / (1.f + __expf(-(si + b2)));
    }
  }
  // ---- Asrc (Wes1 rows 0..63)
  {
#pragma unroll
    for (int jt = 0; jt < 4; ++jt) {
      bf16x8 b0 = bfrag_w(Wes1, 0, jt * 16, lane15, quad);
      bf16x8 b1 = bfrag_w(Wes1, 32, jt * 16, lane15, quad);
      f32x4 z = {0.f, 0.f, 0.f, 0.f};
      z = __builtin_amdgcn_mfma_f32_16x16x32_bf16(A0, b0, z, 0, 0, 0);
      z = __builtin_amdgcn_mfma_f32_16x16x32_bf16(A1, b1, z, 0, 0, 0);
#pragma unroll
      for (int i = 0; i < 4; ++i) {
        int r = m0 + quad * 4 + i;
        if (r < NN) Asrc[(size_t)r * HD + jt * 16 + lane15] = f2bf(z[i]);
      }
    }
  }
  // ---- Adst (Wes1 rows 64..127)
  {
    const float* W = Wes1 + 64 * HD;
#pragma unroll
    for (int jt = 0; jt < 4; ++jt) {
      bf16x8 b0 = bfrag_w(W, 0, jt * 16, lane15, quad);
      bf16x8 b1 = bfrag_w(W, 32, jt * 16, lane15, quad);
      f32x4 z = {0.f, 0.f, 0.f, 0.f};
      z = __builtin_amdgcn_mfma_f32_16x16x32_bf16(A0, b0, z, 0, 0, 0);
      z = __builtin_amdgcn_mfma_f32_16x16x32_bf16(A1, b1, z, 0, 0, 0);
#pragma unroll
      for (int i = 0; i < 4; ++i) {
        int r = m0 + quad * 4 + i;
        if (r < NN) Adst[(size_t)r * HD + jt * 16 + lane15] = f2bf(z[i]);
      }
    }
  }
  // ---- h_out: exact f32 pass
  {
    int r = t >> 2, p = t & 3;
    int gr = n0 + r;
    int grc = gr < NN ? gr : NN - 1;
    const float* rp = ht + (size_t)grc * HD + p * 16;
    float4 v0 = *(const float4*)(rp + 0);
    float4 v1 = *(const float4*)(rp + 4);
    float4 v2 = *(const float4*)(rp + 8);
    float4 v3 = *(const float4*)(rp + 12);
    float ssq = v0.x*v0.x + v0.y*v0.y + v0.z*v0.z + v0.w*v0.w
              + v1.x*v1.x + v1.y*v1.y + v1.z*v1.z + v1.w*v1.w
              + v2.x*v2.x + v2.y*v2.y + v2.z*v2.z + v2.w*v2.w
              + v3.x*v3.x + v3.y*v3.y + v3.z*v3.z + v3.w*v3.w;
    ssq += __shfl_xor(ssq, 1, 64);
    ssq += __shfl_xor(ssq, 2, 64);
    float nu = fmaxf(sqrtf(ssq), 1e-15f);
    float hs = tanhf(nu) / nu;
    if (gr < NN) {
      float* op = h_out + (size_t)gr * HD + p * 16;
      *(float4*)(op + 0)  = make_float4(v0.x*hs, v0.y*hs, v0.z*hs, v0.w*hs);
      *(float4*)(op + 4)  = make_float4(v1.x*hs, v1.y*hs, v1.z*hs, v1.w*hs);
      *(float4*)(op + 8)  = make_float4(v2.x*hs, v2.y*hs, v2.z*hs, v2.w*hs);
      *(float4*)(op + 12) = make_float4(v3.x*hs, v3.y*hs, v3.z*hs, v3.w*hs);
    }
  }
}

// ---------------------------------------------------------------- edge scores (8 lanes/edge, 8 edges/wave)
__global__ void __launch_bounds__(256) k_edge(const int* __restrict__ src,
                                              const int* __restrict__ dst,
                                              const int* __restrict__ etype,
                                              const ushort* __restrict__ Asrc,
                                              const ushort* __restrict__ Adst,
                                              const float* __restrict__ Te2,
                                              const float* __restrict__ Wes2,
                                              const float* __restrict__ bes2,
                                              float* __restrict__ edge_scores) {
  int t = threadIdx.x;
  int lane = t & 63;
  int lq = lane & 7, lg = lane >> 3;
  int w = (blockIdx.x * 256 + t) >> 6;
  int e = w * 8 + lg;
  float p = 0.f;
  if (e < NE) {
    int si = src[e], di = dst[e], ti = etype[e];
    uint4 av = *(const uint4*)&Asrc[(size_t)si * HD + lq * 8];
    uint4 bv = *(const uint4*)&Adst[(size_t)di * HD + lq * 8];
    const float* tp = &Te2[ti * HD + lq * 8];
    float4 t0 = *(const float4*)tp;
    float4 t1 = *(const float4*)(tp + 4);
    const float* wp = &Wes2[lq * 8];
    float4 w0 = *(const float4*)wp;
    float4 w1 = *(const float4*)(wp + 4);
    p += fmaxf(bflo(av.x) + bflo(bv.x) + t0.x, 0.f) * w0.x;
    p += fmaxf(bfhi(av.x) + bfhi(bv.x) + t0.y, 0.f) * w0.y;
    p += fmaxf(bflo(av.y) + bflo(bv.y) + t0.z, 0.f) * w0.z;
    p += fmaxf(bfhi(av.y) + bfhi(bv.y) + t0.w, 0.f) * w0.w;
    p += fmaxf(bflo(av.z) + bflo(bv.z) + t1.x, 0.f) * w1.x;
    p += fmaxf(bfhi(av.z) + bfhi(bv.z) + t1.y, 0.f) * w1.y;
    p += fmaxf(bflo(av.w) + bflo(bv.w) + t1.z, 0.f) * w1.z;
    p += fmaxf(bfhi(av.w) + bfhi(bv.w) + t1.w, 0.f) * w1.w;
  }
  p += __shfl_xor(p, 1, 64);
  p += __shfl_xor(p, 2, 64);
  p += __shfl_xor(p, 4, 64);
  if (e < NE && lq == 0) edge_scores[e] = 1.f / (1.f + __expf(-(p + bes2[0])));
}

// ---------------------------------------------------------------- launch
extern "C" void kernel_launch(void* const* d_in, const int* in_sizes, int n_in,
                              void* d_out, int out_size, void* d_ws, size_t ws_size,
                              hipStream_t stream) {
  const float* node_features = (const float*)d_in[0];
  const float* edge_desc = (const float*)d_in[1];
  const float* query = (const float*)d_in[2];
  const float* Wn = (const float*)d_in[3];
  const float* bn = (const float*)d_in[4];
  const float* ts = (const float*)d_in[5];
  const float* Wq = (const float*)d_in[6];
  const float* bq = (const float*)d_in[7];
  const float* Ws_ = (const float*)d_in[8];
  const float* bs = (const float*)d_in[9];
  const float* attn_a = (const float*)d_in[10];
  const float* Wmp = (const float*)d_in[11];
  const float* bmp = (const float*)d_in[12];
  const float* Wns1 = (const float*)d_in[13];
  const float* bns1 = (const float*)d_in[14];
  const float* Wns2 = (const float*)d_in[15];
  const float* bns2 = (const float*)d_in[16];
  const float* Wes1 = (const float*)d_in[17];
  const float* bes1 = (const float*)d_in[18];
  const float* Wes2 = (const float*)d_in[19];
  const float* bes2 = (const float*)d_in[20];
  const int* edge_index = (const int*)d_in[21];
  const int* etype = (const int*)d_in[22];
  const int* src = edge_index;
  const int* dst = edge_index + NE;

  float* out_ns = (float*)d_out;
  float* out_es = out_ns + NN;
  float* out_h = out_es + NE;
  float* out_te = out_h + (size_t)NN * HD;

  char* w = (char*)d_ws;
  auto alloc = [&](size_t bytes) {
    char* p = w;
    w += (bytes + 1023) & ~(size_t)1023;
    return p;
  };
  float* ht_a = (float*)alloc((size_t)NN * HD * 4);
  float* ht_b = (float*)alloc((size_t)NN * HD * 4);
  ushort* msgbf = (ushort*)alloc((size_t)NN * HD * 2);
  ushort* Asrc = (ushort*)alloc((size_t)NN * HD * 2);
  ushort* Adst = (ushort*)alloc((size_t)NN * HD * 2);
  float* p_src = (float*)alloc(NN * 4);
  float* p_dst = (float*)alloc(NN * 4);
  float* s_buf = (float*)alloc(NE * 4);
  float* qb = (float*)alloc(HD * 4);
  float* qe = (float*)alloc(HD * 4);
  float* ta3 = (float*)alloc(NLAY * NTT * 4);
  float* Te2 = (float*)alloc(NTT * HD * 4);
  int* cnt = (int*)alloc(NN * 4);
  int* row_ptr = (int*)alloc((NN + 1) * 4);
  int* cursor = (int*)alloc(NN * 4);
  int* bsum = (int*)alloc(NCHUNK * 4);
  int* boff = (int*)alloc(NCHUNK * 4);
  int* bucket_cursor = (int*)alloc(NBUCK * 4);
  uint* csr = (uint*)alloc(NE * 4);
  // ebuf (NE x 8B = 6.4 MB) aliases Asrc+Adst (12.8 MB): CSR build finishes
  // before k_score ever writes Asrc/Adst. No overlap in stream order.
  uint2* ebuf = (uint2*)Asrc;

  hipMemsetAsync(cnt, 0, NN * 4, stream);
  k_setup<<<1, 256, 0, stream>>>(edge_desc, query, Wq, bq, Ws_, bs, attn_a, Wns1, bns1,
                                 Wes1, bes1, out_te, qb, ta3, qe);
  k_te2<<<16, 256, 0, stream>>>(out_te, qe, Wes1, Te2);
  k_hist<<<NE / 256, 256, 0, stream>>>(dst, cnt);
  k_scanA<<<NCHUNK, 256, 0, stream>>>(cnt, bsum);
  k_scanB<<<1, 64, 0, stream>>>(bsum, boff, row_ptr);
  k_scanC<<<NCHUNK, 256, 0, stream>>>(cnt, boff, row_ptr, cursor);
  k_binit<<<1, 256, 0, stream>>>(row_ptr, bucket_cursor);
  k_bin<<<NBINBLK, 256, 0, stream>>>(src, dst, etype, bucket_cursor, ebuf);
  k_scatter2<<<NBUCK, 256, 0, stream>>>(row_ptr, ebuf, cursor, csr);
  k_proj<<<(NN + 63) / 64, 256, 0, stream>>>(node_features, Wn, bn, ts, ht_a);

  float* cur = ht_a;
  float* nxt = ht_b;
  for (int l = 0; l < NLAY; ++l) {
    k_msg<<<(NN + 63) / 64, 256, 0, stream>>>(cur, Wmp + l * HD * HD, bmp + l * HD,
                                              attn_a + l * (2 * HD + TDD), msgbf, p_src, p_dst);
    k_agg<<<(NN + 3) / 4, 256, 0, stream>>>(row_ptr, csr, p_src, p_dst, ta3 + l * NTT,
                                            msgbf, nxt, s_buf);
    float* tmp = cur; cur = nxt; nxt = tmp;
  }
  k_score<<<(NN + 63) / 64, 256, 0, stream>>>(cur, Wns1, qb, Wns2, bns2, Wes1,
                                              out_ns, out_h, Asrc, Adst);
  k_edge<<<(NE + 31) / 32, 256, 0, stream>>>(src, dst, etype, Asrc, Adst, Te2,
                                             Wes2, bes2, out_es);
}

// Round 9
// 394.355 us; speedup vs baseline: 1.4212x; 1.0439x over previous
//
#include <hip/hip_runtime.h>
#include <math.h>

#define NN 50000
#define NE 800000
#define NFD 256
#define HD 64
#define QDD 128
#define TDD 32
#define NTT 64
#define NLAY 3
#define LCLAMP 6.1030340f   // atanh(1 - 1e-5)
#define CHUNK 1024
#define NCHUNK 49           // ceil(50000/1024)
#define NBUCK 196           // ceil(50000/256) coarse buckets (dst >> 8)
#define EPB 4096            // edges per k_bin block
#define NBINBLK 196         // ceil(800000/4096)
#define PST 72              // k_proj LDS tile stride (shorts for staging, floats for epilogue)

typedef unsigned int uint;
typedef unsigned short ushort;
typedef __attribute__((ext_vector_type(8))) short bf16x8;
typedef __attribute__((ext_vector_type(4))) float f32x4;

__device__ __forceinline__ ushort f2bf(float f) {
  uint u = __float_as_uint(f);
  uint r = (u + 0x7FFFu + ((u >> 16) & 1u)) >> 16;
  return (ushort)r;
}
__device__ __forceinline__ short f2bfs(float f) { return (short)f2bf(f); }
__device__ __forceinline__ float bf2f(short s) { return __uint_as_float(((uint)(ushort)s) << 16); }
__device__ __forceinline__ float bflo(uint w) { return __uint_as_float(w << 16); }
__device__ __forceinline__ float bfhi(uint w) { return __uint_as_float(w & 0xFFFF0000u); }

// A-frag from 8 consecutive f32
__device__ __forceinline__ bf16x8 frag_f32(const float* p) {
  float4 a = *(const float4*)p;
  float4 b = *(const float4*)(p + 4);
  bf16x8 r;
  r[0] = f2bfs(a.x); r[1] = f2bfs(a.y); r[2] = f2bfs(a.z); r[3] = f2bfs(a.w);
  r[4] = f2bfs(b.x); r[5] = f2bfs(b.y); r[6] = f2bfs(b.z); r[7] = f2bfs(b.w);
  return r;
}
// B-frag from row-major W[K][64]: k=k0+quad*8+j, n=j0+lane15
__device__ __forceinline__ bf16x8 bfrag_w(const float* W, int k0, int j0, int lane15, int quad) {
  bf16x8 r;
#pragma unroll
  for (int j = 0; j < 8; ++j) r[j] = f2bfs(W[(k0 + quad * 8 + j) * HD + j0 + lane15]);
  return r;
}

// ---------------------------------------------------------------- setup
__global__ void k_setup(const float* __restrict__ edge_desc, const float* __restrict__ query,
                        const float* __restrict__ Wq, const float* __restrict__ bq,
                        const float* __restrict__ Ws, const float* __restrict__ bs,
                        const float* __restrict__ attn_a,
                        const float* __restrict__ Wns1, const float* __restrict__ bns1,
                        const float* __restrict__ Wes1, const float* __restrict__ bes1,
                        float* __restrict__ out_type_emb,
                        float* __restrict__ qb, float* __restrict__ ta3,
                        float* __restrict__ qe) {
  __shared__ float te_l[NTT * TDD];
  __shared__ float q_l[HD];
  int t = threadIdx.x;
  if (t < HD) {
    float acc = bq[t];
    for (int k = 0; k < QDD; ++k) acc += query[k] * Wq[k * HD + t];
    q_l[t] = acc;
  }
  for (int idx = t; idx < NTT * TDD; idx += 256) {
    int ty = idx / TDD, d = idx % TDD;
    float acc = bs[d];
    for (int k = 0; k < 64; ++k) acc += edge_desc[ty * 64 + k] * Ws[k * TDD + d];
    float v = tanhf(acc);
    te_l[idx] = v;
    out_type_emb[idx] = v;
  }
  __syncthreads();
  if (t < NLAY * NTT) {
    int l = t / NTT, ty = t % NTT;
    float acc = 0.f;
    for (int d = 0; d < TDD; ++d) acc += te_l[ty * TDD + d] * attn_a[l * (2 * HD + TDD) + 2 * HD + d];
    ta3[t] = acc;
  }
  if (t < HD) {
    float a1 = bns1[t], a2 = bes1[t];
    for (int k = 0; k < HD; ++k) {
      a1 += q_l[k] * Wns1[(HD + k) * HD + t];
      a2 += q_l[k] * Wes1[(2 * HD + TDD + k) * HD + t];
    }
    qb[t] = a1;
    qe[t] = a2;
  }
}

// Te2bf[ty][j] = bf16(type_emb[ty] @ Wes1[te-part] + qe)
__global__ void k_te2(const float* __restrict__ te, const float* __restrict__ qe,
                      const float* __restrict__ Wes1, ushort* __restrict__ Te2bf) {
  int idx = blockIdx.x * 256 + threadIdx.x;   // 4096 total
  int ty = idx >> 6, j = idx & 63;
  float acc = qe[j];
#pragma unroll
  for (int d = 0; d < TDD; ++d) acc += te[ty * TDD + d] * Wes1[(2 * HD + d) * HD + j];
  Te2bf[idx] = f2bf(acc);
}

// ---------------------------------------------------------------- CSR build
__global__ void k_hist(const int* __restrict__ dst, int* __restrict__ cnt) {
  int e = blockIdx.x * 256 + threadIdx.x;
  if (e < NE) atomicAdd(&cnt[dst[e]], 1);
}

__global__ void k_scanA(const int* __restrict__ cnt, int* __restrict__ bsum) {
  __shared__ int ws[4];
  int t = threadIdx.x;
  int c0 = blockIdx.x * CHUNK;
  int s = 0;
#pragma unroll
  for (int it = 0; it < 4; ++it) {
    int i = c0 + it * 256 + t;
    if (i < NN) s += cnt[i];
  }
#pragma unroll
  for (int off = 1; off < 64; off <<= 1) s += __shfl_xor(s, off, 64);
  if ((t & 63) == 0) ws[t >> 6] = s;
  __syncthreads();
  if (t == 0) bsum[blockIdx.x] = ws[0] + ws[1] + ws[2] + ws[3];
}

__global__ void k_scanB(const int* __restrict__ bsum, int* __restrict__ boff,
                        int* __restrict__ row_ptr) {
  int t = threadIdx.x;  // 64 threads
  int v = (t < NCHUNK) ? bsum[t] : 0;
  int x = v;
#pragma unroll
  for (int off = 1; off < 64; off <<= 1) {
    int y = __shfl_up(x, off, 64);
    if (t >= off) x += y;
  }
  if (t < NCHUNK) boff[t] = x - v;
  if (t == 63) row_ptr[NN] = x;
}

// also emits bucket_cursor[b] = row_ptr[b*256] (k_binit merged in)
__global__ void k_scanC(const int* __restrict__ cnt, const int* __restrict__ boff,
                        int* __restrict__ row_ptr, int* __restrict__ bucket_cursor) {
  __shared__ int wsum[4], woff_s[4];
  int t = threadIdx.x;
  int c0 = blockIdx.x * CHUNK;
  int i0 = c0 + t * 4;
  int v0 = (i0 + 0 < NN) ? cnt[i0 + 0] : 0;
  int v1 = (i0 + 1 < NN) ? cnt[i0 + 1] : 0;
  int v2 = (i0 + 2 < NN) ? cnt[i0 + 2] : 0;
  int v3 = (i0 + 3 < NN) ? cnt[i0 + 3] : 0;
  int s4 = v0 + v1 + v2 + v3;
  int lane = t & 63, wid = t >> 6;
  int x = s4;
#pragma unroll
  for (int off = 1; off < 64; off <<= 1) {
    int y = __shfl_up(x, off, 64);
    if (lane >= off) x += y;
  }
  if (lane == 63) wsum[wid] = x;
  __syncthreads();
  if (t == 0) {
    int a = 0;
    for (int i = 0; i < 4; ++i) { woff_s[i] = a; a += wsum[i]; }
  }
  __syncthreads();
  int base = boff[blockIdx.x] + woff_s[wid] + (x - s4);
  int r0 = base, r1 = base + v0, r2 = r1 + v1, r3 = r2 + v2;
  if (i0 + 0 < NN) {
    row_ptr[i0 + 0] = r0;
    if ((i0 & 255) == 0) bucket_cursor[i0 >> 8] = r0;
  }
  if (i0 + 1 < NN) row_ptr[i0 + 1] = r1;
  if (i0 + 2 < NN) row_ptr[i0 + 2] = r2;
  if (i0 + 3 < NN) row_ptr[i0 + 3] = r3;
}

// phase B: bin edges by coarse bucket (dst>>8) into packed ebuf.
// pack: src(16) | type(6)<<16 | (dst&255)<<22
__global__ void __launch_bounds__(256) k_bin(const int* __restrict__ src,
                                             const int* __restrict__ dst,
                                             const int* __restrict__ etype,
                                             int* __restrict__ bucket_cursor,
                                             uint* __restrict__ ebuf) {
  __shared__ int cntl[NBUCK];
  __shared__ int gbase[NBUCK];
  int t = threadIdx.x;
  for (int i = t; i < NBUCK; i += 256) cntl[i] = 0;
  __syncthreads();
  int e0 = blockIdx.x * EPB;
  int dd[16];
  uint pk[16];
  int rk[16];
#pragma unroll
  for (int c = 0; c < 4; ++c) {
    int eb = e0 + c * 1024 + t * 4;
    if (eb < NE) {   // NE%4==0 => eb<NE implies eb+3<NE
      int4 s4 = *(const int4*)&src[eb];
      int4 d4 = *(const int4*)&dst[eb];
      int4 y4 = *(const int4*)&etype[eb];
      int ds[4] = {d4.x, d4.y, d4.z, d4.w};
      int ss[4] = {s4.x, s4.y, s4.z, s4.w};
      int ys[4] = {y4.x, y4.y, y4.z, y4.w};
#pragma unroll
      for (int j = 0; j < 4; ++j) {
        int idx = c * 4 + j;
        int d = ds[j];
        dd[idx] = d;
        pk[idx] = (uint)ss[j] | ((uint)ys[j] << 16) | ((uint)(d & 255) << 22);
        rk[idx] = atomicAdd(&cntl[d >> 8], 1);
      }
    } else {
#pragma unroll
      for (int j = 0; j < 4; ++j) dd[c * 4 + j] = -1;
    }
  }
  __syncthreads();
  if (t < NBUCK && cntl[t] > 0) gbase[t] = atomicAdd(&bucket_cursor[t], cntl[t]);
  __syncthreads();
#pragma unroll
  for (int i = 0; i < 16; ++i) {
    if (dd[i] >= 0) ebuf[gbase[dd[i] >> 8] + rk[i]] = pk[i];
  }
}

// phase C: per-bucket scatter to final CSR slot; per-node cursors in LDS
__global__ void __launch_bounds__(256) k_scatter2(const int* __restrict__ row_ptr,
                                                  const uint* __restrict__ ebuf,
                                                  uint* __restrict__ csr) {
  __shared__ int curs[256];
  int b = blockIdx.x;
  int n0 = b << 8;
  int t = threadIdx.x;
  int n = n0 + t;
  curs[t] = (n < NN) ? row_ptr[n] : 0;
  __syncthreads();
  int n1 = n0 + 256; if (n1 > NN) n1 = NN;
  int lo = row_ptr[n0];
  int hi = row_ptr[n1];
  for (int i = lo + t; i < hi; i += 256) {
    uint v = ebuf[i];
    int j = (v >> 22) & 255;
    int pos = atomicAdd(&curs[j], 1);
    csr[pos] = v & 0x3FFFFFu;
  }
}

// ---------------------------------------------------------------- k_proj (MFMA, pipelined staging)
// + fused layer-0 k_msg: ht0 tile is already in LDS, so also emit msgbf/p_src/p_dst.
__global__ void __launch_bounds__(256) k_proj(const float* __restrict__ X,
                                              const float* __restrict__ Wn,
                                              const float* __restrict__ bn,
                                              const float* __restrict__ ts_p,
                                              float* __restrict__ ht0,
                                              const float* __restrict__ Wmp0,
                                              const float* __restrict__ bmp0,
                                              const float* __restrict__ attn0,
                                              ushort* __restrict__ msgbf,
                                              float* __restrict__ p_src,
                                              float* __restrict__ p_dst) {
  __shared__ ushort buf[2][64 * PST];            // 2 x 9216 B
  float* st = (float*)&buf[0][0];                // epilogue alias: 64 x 72 f32
  int t = threadIdx.x;
  int lane = t & 63, wv = t >> 6;
  int lane15 = lane & 15, quad = lane >> 4;
  int n0 = blockIdx.x * 64;
  int j0 = wv * 16;
  bf16x8 B[8];
#pragma unroll
  for (int fb = 0; fb < 8; ++fb) B[fb] = bfrag_w(Wn, fb * 32, j0, lane15, quad);

  int srow = t >> 2;
  int scg = (t & 3) * 16;
  int grow = n0 + srow; if (grow >= NN) grow = NN - 1;
  const float* xrow = X + (size_t)grow * NFD + scg;

  f32x4 acc[4];
#pragma unroll
  for (int mt = 0; mt < 4; ++mt) acc[mt] = (f32x4){0.f, 0.f, 0.f, 0.f};

  float4 r0 = *(const float4*)(xrow + 0);
  float4 r1 = *(const float4*)(xrow + 4);
  float4 r2 = *(const float4*)(xrow + 8);
  float4 r3 = *(const float4*)(xrow + 12);

  for (int c = 0; c < 4; ++c) {
    ushort* wp = &buf[c & 1][srow * PST + scg];
    uint4 o0, o1;
    o0.x = (uint)f2bf(r0.x) | ((uint)f2bf(r0.y) << 16);
    o0.y = (uint)f2bf(r0.z) | ((uint)f2bf(r0.w) << 16);
    o0.z = (uint)f2bf(r1.x) | ((uint)f2bf(r1.y) << 16);
    o0.w = (uint)f2bf(r1.z) | ((uint)f2bf(r1.w) << 16);
    o1.x = (uint)f2bf(r2.x) | ((uint)f2bf(r2.y) << 16);
    o1.y = (uint)f2bf(r2.z) | ((uint)f2bf(r2.w) << 16);
    o1.z = (uint)f2bf(r3.x) | ((uint)f2bf(r3.y) << 16);
    o1.w = (uint)f2bf(r3.z) | ((uint)f2bf(r3.w) << 16);
    *(uint4*)wp = o0;
    *(uint4*)(wp + 8) = o1;
    if (c < 3) {
      const float* nx = xrow + (c + 1) * 64;
      r0 = *(const float4*)(nx + 0);
      r1 = *(const float4*)(nx + 4);
      r2 = *(const float4*)(nx + 8);
      r3 = *(const float4*)(nx + 12);
    }
    __syncthreads();
    const ushort* bp = &buf[c & 1][0];
#pragma unroll
    for (int mt = 0; mt < 4; ++mt) {
#pragma unroll
      for (int ks = 0; ks < 2; ++ks) {
        bf16x8 A = *(const bf16x8*)&bp[(mt * 16 + lane15) * PST + ks * 32 + quad * 8];
        acc[mt] = __builtin_amdgcn_mfma_f32_16x16x32_bf16(A, B[c * 2 + ks], acc[mt], 0, 0, 0);
      }
    }
  }
  __syncthreads();
  // epilogue: (acc+bn)*ts into st, norm-clamp, write ht0, write scaled back to st
  float ts = ts_p[0];
  float vb = bn[j0 + lane15];
#pragma unroll
  for (int mt = 0; mt < 4; ++mt)
#pragma unroll
    for (int i = 0; i < 4; ++i)
      st[(mt * 16 + quad * 4 + i) * PST + j0 + lane15] = (acc[mt][i] + vb) * ts;
  __syncthreads();
  {
    int r = t >> 2, p = t & 3;
    float* rp = &st[r * PST + p * 16];
    float4 v0 = *(const float4*)(rp + 0);
    float4 v1 = *(const float4*)(rp + 4);
    float4 v2 = *(const float4*)(rp + 8);
    float4 v3 = *(const float4*)(rp + 12);
    float ssq = v0.x*v0.x + v0.y*v0.y + v0.z*v0.z + v0.w*v0.w
              + v1.x*v1.x + v1.y*v1.y + v1.z*v1.z + v1.w*v1.w
              + v2.x*v2.x + v2.y*v2.y + v2.z*v2.z + v2.w*v2.w
              + v3.x*v3.x + v3.y*v3.y + v3.z*v3.z + v3.w*v3.w;
    ssq += __shfl_xor(ssq, 1, 64);
    ssq += __shfl_xor(ssq, 2, 64);
    float nu = fmaxf(sqrtf(ssq), 1e-15f);
    float sc = fminf(nu, LCLAMP) / nu;
    float4 w0 = make_float4(v0.x*sc, v0.y*sc, v0.z*sc, v0.w*sc);
    float4 w1 = make_float4(v1.x*sc, v1.y*sc, v1.z*sc, v1.w*sc);
    float4 w2 = make_float4(v2.x*sc, v2.y*sc, v2.z*sc, v2.w*sc);
    float4 w3 = make_float4(v3.x*sc, v3.y*sc, v3.z*sc, v3.w*sc);
    int orow = n0 + r;
    if (orow < NN) {
      float* op = &ht0[(size_t)orow * HD + p * 16];
      *(float4*)(op + 0) = w0; *(float4*)(op + 4) = w1;
      *(float4*)(op + 8) = w2; *(float4*)(op + 12) = w3;
    }
    *(float4*)(rp + 0) = w0; *(float4*)(rp + 4) = w1;
    *(float4*)(rp + 8) = w2; *(float4*)(rp + 12) = w3;
  }
  __syncthreads();
  // fused layer-0 msg: wave handles 16 rows of the tile (all in st, scaled)
  {
    bf16x8 Bm0[4], Bm1[4];
    float vbm[4];
#pragma unroll
    for (int jt = 0; jt < 4; ++jt) {
      Bm0[jt] = bfrag_w(Wmp0, 0, jt * 16, lane15, quad);
      Bm1[jt] = bfrag_w(Wmp0, 32, jt * 16, lane15, quad);
      vbm[jt] = bmp0[jt * 16 + lane15];
    }
    int mrow = wv * 16 + lane15;
    bf16x8 A0 = frag_f32(&st[mrow * PST + quad * 8]);
    bf16x8 A1 = frag_f32(&st[mrow * PST + 32 + quad * 8]);
#pragma unroll
    for (int jt = 0; jt < 4; ++jt) {
      f32x4 z = {0.f, 0.f, 0.f, 0.f};
      z = __builtin_amdgcn_mfma_f32_16x16x32_bf16(A0, Bm0[jt], z, 0, 0, 0);
      z = __builtin_amdgcn_mfma_f32_16x16x32_bf16(A1, Bm1[jt], z, 0, 0, 0);
#pragma unroll
      for (int i = 0; i < 4; ++i) {
        int r = n0 + wv * 16 + quad * 4 + i;
        if (r < NN) msgbf[(size_t)r * HD + jt * 16 + lane15] = f2bf(z[i] + vbm[jt]);
      }
    }
    float4 a1l = *(const float4*)&attn0[quad * 8];
    float4 a1h = *(const float4*)&attn0[quad * 8 + 4];
    float4 a1l2 = *(const float4*)&attn0[32 + quad * 8];
    float4 a1h2 = *(const float4*)&attn0[32 + quad * 8 + 4];
    float4 a2l = *(const float4*)&attn0[64 + quad * 8];
    float4 a2h = *(const float4*)&attn0[64 + quad * 8 + 4];
    float4 a2l2 = *(const float4*)&attn0[96 + quad * 8];
    float4 a2h2 = *(const float4*)&attn0[96 + quad * 8 + 4];
    float p1 = bf2f(A0[0])*a1l.x + bf2f(A0[1])*a1l.y + bf2f(A0[2])*a1l.z + bf2f(A0[3])*a1l.w
             + bf2f(A0[4])*a1h.x + bf2f(A0[5])*a1h.y + bf2f(A0[6])*a1h.z + bf2f(A0[7])*a1h.w
             + bf2f(A1[0])*a1l2.x + bf2f(A1[1])*a1l2.y + bf2f(A1[2])*a1l2.z + bf2f(A1[3])*a1l2.w
             + bf2f(A1[4])*a1h2.x + bf2f(A1[5])*a1h2.y + bf2f(A1[6])*a1h2.z + bf2f(A1[7])*a1h2.w;
    float p2 = bf2f(A0[0])*a2l.x + bf2f(A0[1])*a2l.y + bf2f(A0[2])*a2l.z + bf2f(A0[3])*a2l.w
             + bf2f(A0[4])*a2h.x + bf2f(A0[5])*a2h.y + bf2f(A0[6])*a2h.z + bf2f(A0[7])*a2h.w
             + bf2f(A1[0])*a2l2.x + bf2f(A1[1])*a2l2.y + bf2f(A1[2])*a2l2.z + bf2f(A1[3])*a2l2.w
             + bf2f(A1[4])*a2h2.x + bf2f(A1[5])*a2h2.y + bf2f(A1[6])*a2h2.z + bf2f(A1[7])*a2h2.w;
    p1 += __shfl_xor(p1, 16, 64); p1 += __shfl_xor(p1, 32, 64);
    p2 += __shfl_xor(p2, 16, 64); p2 += __shfl_xor(p2, 32, 64);
    int prow = n0 + mrow;
    if (quad == 0 && prow < NN) { p_src[prow] = p1; p_dst[prow] = p2; }
  }
}

// ---------------------------------------------------------------- msg = ht @ Wmp + bmp (bf16); p_src/p_dst (MFMA)
__global__ void __launch_bounds__(256) k_msg(const float* __restrict__ ht,
                                             const float* __restrict__ Wmp_l,
                                             const float* __restrict__ bmp_l,
                                             const float* __restrict__ attn_l,
                                             ushort* __restrict__ msgbf,
                                             float* __restrict__ p_src,
                                             float* __restrict__ p_dst) {
  int t = threadIdx.x;
  int lane = t & 63, wv = t >> 6;
  int lane15 = lane & 15, quad = lane >> 4;
  int m0 = blockIdx.x * 64 + wv * 16;
  bf16x8 B[4][2];
  float vb[4];
#pragma unroll
  for (int jt = 0; jt < 4; ++jt) {
    B[jt][0] = bfrag_w(Wmp_l, 0, jt * 16, lane15, quad);
    B[jt][1] = bfrag_w(Wmp_l, 32, jt * 16, lane15, quad);
    vb[jt] = bmp_l[jt * 16 + lane15];
  }
  int row = m0 + lane15;
  int rowc = row < NN ? row : NN - 1;
  bf16x8 A0 = frag_f32(ht + (size_t)rowc * HD + quad * 8);
  bf16x8 A1 = frag_f32(ht + (size_t)rowc * HD + 32 + quad * 8);
  f32x4 acc[4];
#pragma unroll
  for (int jt = 0; jt < 4; ++jt) {
    f32x4 z = {0.f, 0.f, 0.f, 0.f};
    z = __builtin_amdgcn_mfma_f32_16x16x32_bf16(A0, B[jt][0], z, 0, 0, 0);
    z = __builtin_amdgcn_mfma_f32_16x16x32_bf16(A1, B[jt][1], z, 0, 0, 0);
    acc[jt] = z;
  }
#pragma unroll
  for (int jt = 0; jt < 4; ++jt)
#pragma unroll
    for (int i = 0; i < 4; ++i) {
      int r = m0 + quad * 4 + i;
      if (r < NN) msgbf[(size_t)r * HD + jt * 16 + lane15] = f2bf(acc[jt][i] + vb[jt]);
    }
  float4 a1l = *(const float4*)&attn_l[quad * 8];
  float4 a1h = *(const float4*)&attn_l[quad * 8 + 4];
  float4 a1l2 = *(const float4*)&attn_l[32 + quad * 8];
  float4 a1h2 = *(const float4*)&attn_l[32 + quad * 8 + 4];
  float4 a2l = *(const float4*)&attn_l[64 + quad * 8];
  float4 a2h = *(const float4*)&attn_l[64 + quad * 8 + 4];
  float4 a2l2 = *(const float4*)&attn_l[96 + quad * 8];
  float4 a2h2 = *(const float4*)&attn_l[96 + quad * 8 + 4];
  float p1 = bf2f(A0[0])*a1l.x + bf2f(A0[1])*a1l.y + bf2f(A0[2])*a1l.z + bf2f(A0[3])*a1l.w
           + bf2f(A0[4])*a1h.x + bf2f(A0[5])*a1h.y + bf2f(A0[6])*a1h.z + bf2f(A0[7])*a1h.w
           + bf2f(A1[0])*a1l2.x + bf2f(A1[1])*a1l2.y + bf2f(A1[2])*a1l2.z + bf2f(A1[3])*a1l2.w
           + bf2f(A1[4])*a1h2.x + bf2f(A1[5])*a1h2.y + bf2f(A1[6])*a1h2.z + bf2f(A1[7])*a1h2.w;
  float p2 = bf2f(A0[0])*a2l.x + bf2f(A0[1])*a2l.y + bf2f(A0[2])*a2l.z + bf2f(A0[3])*a2l.w
           + bf2f(A0[4])*a2h.x + bf2f(A0[5])*a2h.y + bf2f(A0[6])*a2h.z + bf2f(A0[7])*a2h.w
           + bf2f(A1[0])*a2l2.x + bf2f(A1[1])*a2l2.y + bf2f(A1[2])*a2l2.z + bf2f(A1[3])*a2l2.w
           + bf2f(A1[4])*a2h2.x + bf2f(A1[5])*a2h2.y + bf2f(A1[6])*a2h2.z + bf2f(A1[7])*a2h2.w;
  p1 += __shfl_xor(p1, 16, 64); p1 += __shfl_xor(p1, 32, 64);
  p2 += __shfl_xor(p2, 16, 64); p2 += __shfl_xor(p2, 32, 64);
  if (quad == 0 && row < NN) { p_src[row] = p1; p_dst[row] = p2; }
}

// ---------------------------------------------------------------- softmax-aggregate (wave/node, 8-wide gather)
__global__ void __launch_bounds__(256) k_agg(const int* __restrict__ row_ptr,
                                             const uint* __restrict__ csr,
                                             const float* __restrict__ p_src,
                                             const float* __restrict__ p_dst,
                                             const float* __restrict__ ta_l,
                                             const ushort* __restrict__ msgbf,
                                             float* __restrict__ ht_out,
                                             float* __restrict__ s_buf) {
  int lane = threadIdx.x & 63;
  int n = (blockIdx.x * 256 + threadIdx.x) >> 6;
  if (n >= NN) return;
  int start = row_ptr[n], end = row_ptr[n + 1];
  int deg = end - start;
  float pd = p_dst[n];
  int lq = lane & 7, lg = lane >> 3;
  float acc[8];
#pragma unroll
  for (int u = 0; u < 8; ++u) acc[u] = 0.f;
  float exsum = 0.f;

  if (deg <= 64) {
    bool valid = lane < deg;
    float s = -3.4e38f;
    int sidx = 0;
    if (valid) {
      uint pk = csr[start + lane];
      sidx = (int)(pk & 0xFFFFu);
      int ty = (int)(pk >> 16);
      float v = p_src[sidx] + pd + ta_l[ty];
      s = (v > 0.f) ? v : 0.2f * v;
    }
    float m = s;
#pragma unroll
    for (int off = 32; off >= 1; off >>= 1) m = fmaxf(m, __shfl_xor(m, off, 64));
    float ex = valid ? __expf(s - m) : 0.f;
    exsum = ex;
    for (int it = 0; it < deg; it += 8) {
      int el = it + lg;
      float exk = __shfl(ex, el, 64);
      int sk = __shfl(sidx, el, 64);
      if (el < deg) {
        uint4 mv = *(const uint4*)&msgbf[(size_t)sk * HD + lq * 8];
        acc[0] += exk * bflo(mv.x); acc[1] += exk * bfhi(mv.x);
        acc[2] += exk * bflo(mv.y); acc[3] += exk * bfhi(mv.y);
        acc[4] += exk * bflo(mv.z); acc[5] += exk * bfhi(mv.z);
        acc[6] += exk * bflo(mv.w); acc[7] += exk * bfhi(mv.w);
      }
    }
  } else {
    float m = -3.4e38f;
    for (int base = start; base < end; base += 64) {
      int i = base + lane;
      float s = -3.4e38f;
      if (i < end) {
        uint pk = csr[i];
        int sidx = (int)(pk & 0xFFFFu);
        int ty = (int)(pk >> 16);
        float v = p_src[sidx] + pd + ta_l[ty];
        s = (v > 0.f) ? v : 0.2f * v;
        s_buf[i] = s;
      }
      m = fmaxf(m, s);
    }
#pragma unroll
    for (int off = 32; off >= 1; off >>= 1) m = fmaxf(m, __shfl_xor(m, off, 64));
    for (int base = start; base < end; base += 64) {
      int i = base + lane;
      if (i < end) {
        float ex = __expf(s_buf[i] - m);
        s_buf[i] = ex;
        exsum += ex;
      }
    }
    for (int it = start; it < end; it += 8) {
      int el = it + lg;
      if (el < end) {
        float exk = s_buf[el];
        int sk = (int)(csr[el] & 0xFFFFu);
        uint4 mv = *(const uint4*)&msgbf[(size_t)sk * HD + lq * 8];
        acc[0] += exk * bflo(mv.x); acc[1] += exk * bfhi(mv.x);
        acc[2] += exk * bflo(mv.y); acc[3] += exk * bfhi(mv.y);
        acc[4] += exk * bflo(mv.z); acc[5] += exk * bfhi(mv.z);
        acc[6] += exk * bflo(mv.w); acc[7] += exk * bfhi(mv.w);
      }
    }
  }
#pragma unroll
  for (int u = 0; u < 8; ++u) {
    acc[u] += __shfl_xor(acc[u], 8, 64);
    acc[u] += __shfl_xor(acc[u], 16, 64);
    acc[u] += __shfl_xor(acc[u], 32, 64);
  }
#pragma unroll
  for (int off = 32; off >= 1; off >>= 1) exsum += __shfl_xor(exsum, off, 64);
  float inv = 1.f / (exsum + 1e-15f);
  float ss = 0.f;
#pragma unroll
  for (int u = 0; u < 8; ++u) {
    float v = fmaxf(acc[u] * inv, 0.f);
    acc[u] = v;
    ss += v * v;
  }
  ss += __shfl_xor(ss, 1, 64);
  ss += __shfl_xor(ss, 2, 64);
  ss += __shfl_xor(ss, 4, 64);
  float nu = fmaxf(sqrtf(ss), 1e-15f);
  float sc = fminf(nu, LCLAMP) / nu;
  if (lane < 8) {
    *(float4*)&ht_out[(size_t)n * HD + lane * 8] =
        make_float4(acc[0] * sc, acc[1] * sc, acc[2] * sc, acc[3] * sc);
    *(float4*)&ht_out[(size_t)n * HD + lane * 8 + 4] =
        make_float4(acc[4] * sc, acc[5] * sc, acc[6] * sc, acc[7] * sc);
  }
}

// ---------------------------------------------------------------- heads (MFMA)
__global__ void __launch_bounds__(256) k_score(const float* __restrict__ ht,
                                               const float* __restrict__ Wns1,
                                               const float* __restrict__ qb,
                                               const float* __restrict__ Wns2,
                                               const float* __restrict__ bns2,
                                               const float* __restrict__ Wes1,
                                               float* __restrict__ node_scores,
                                               float* __restrict__ h_out,
                                               ushort* __restrict__ Asrc,
                                               ushort* __restrict__ Adst) {
  int t = threadIdx.x;
  int lane = t & 63, wv = t >> 6;
  int lane15 = lane & 15, quad = lane >> 4;
  int n0 = blockIdx.x * 64;
  int m0 = n0 + wv * 16;
  int row = m0 + lane15;
  int rowc = row < NN ? row : NN - 1;
  bf16x8 A0 = frag_f32(ht + (size_t)rowc * HD + quad * 8);
  bf16x8 A1 = frag_f32(ht + (size_t)rowc * HD + 32 + quad * 8);

  // node head
  {
    f32x4 acc[4];
#pragma unroll
    for (int jt = 0; jt < 4; ++jt) {
      bf16x8 b0 = bfrag_w(Wns1, 0, jt * 16, lane15, quad);
      bf16x8 b1 = bfrag_w(Wns1, 32, jt * 16, lane15, quad);
      f32x4 z = {0.f, 0.f, 0.f, 0.f};
      z = __builtin_amdgcn_mfma_f32_16x16x32_bf16(A0, b0, z, 0, 0, 0);
      z = __builtin_amdgcn_mfma_f32_16x16x32_bf16(A1, b1, z, 0, 0, 0);
      acc[jt] = z;
    }
    float vqb[4], vw2[4];
#pragma unroll
    for (int jt = 0; jt < 4; ++jt) { vqb[jt] = qb[jt * 16 + lane15]; vw2[jt] = Wns2[jt * 16 + lane15]; }
    float b2 = bns2[0];
#pragma unroll
    for (int i = 0; i < 4; ++i) {
      float si = 0.f;
#pragma unroll
      for (int jt = 0; jt < 4; ++jt) si += fmaxf(acc[jt][i] + vqb[jt], 0.f) * vw2[jt];
      si += __shfl_xor(si, 1, 64);
      si += __shfl_xor(si, 2, 64);
      si += __shfl_xor(si, 4, 64);
      si += __shfl_xor(si, 8, 64);
      int r = m0 + quad * 4 + i;
      if (lane15 == 0 && r < NN) node_scores[r] = 1.f / (1.f + __expf(-(si + b2)));
    }
  }
  // Asrc
  {
#pragma unroll
    for (int jt = 0; jt < 4; ++jt) {
      bf16x8 b0 = bfrag_w(Wes1, 0, jt * 16, lane15, quad);
      bf16x8 b1 = bfrag_w(Wes1, 32, jt * 16, lane15, quad);
      f32x4 z = {0.f, 0.f, 0.f, 0.f};
      z = __builtin_amdgcn_mfma_f32_16x16x32_bf16(A0, b0, z, 0, 0, 0);
      z = __builtin_amdgcn_mfma_f32_16x16x32_bf16(A1, b1, z, 0, 0, 0);
#pragma unroll
      for (int i = 0; i < 4; ++i) {
        int r = m0 + quad * 4 + i;
        if (r < NN) Asrc[(size_t)r * HD + jt * 16 + lane15] = f2bf(z[i]);
      }
    }
  }
  // Adst
  {
    const float* W = Wes1 + 64 * HD;
#pragma unroll
    for (int jt = 0; jt < 4; ++jt) {
      bf16x8 b0 = bfrag_w(W, 0, jt * 16, lane15, quad);
      bf16x8 b1 = bfrag_w(W, 32, jt * 16, lane15, quad);
      f32x4 z = {0.f, 0.f, 0.f, 0.f};
      z = __builtin_amdgcn_mfma_f32_16x16x32_bf16(A0, b0, z, 0, 0, 0);
      z = __builtin_amdgcn_mfma_f32_16x16x32_bf16(A1, b1, z, 0, 0, 0);
#pragma unroll
      for (int i = 0; i < 4; ++i) {
        int r = m0 + quad * 4 + i;
        if (r < NN) Adst[(size_t)r * HD + jt * 16 + lane15] = f2bf(z[i]);
      }
    }
  }
  // h_out: exact f32 pass
  {
    int r = t >> 2, p = t & 3;
    int gr = n0 + r;
    int grc = gr < NN ? gr : NN - 1;
    const float* rp = ht + (size_t)grc * HD + p * 16;
    float4 v0 = *(const float4*)(rp + 0);
    float4 v1 = *(const float4*)(rp + 4);
    float4 v2 = *(const float4*)(rp + 8);
    float4 v3 = *(const float4*)(rp + 12);
    float ssq = v0.x*v0.x + v0.y*v0.y + v0.z*v0.z + v0.w*v0.w
              + v1.x*v1.x + v1.y*v1.y + v1.z*v1.z + v1.w*v1.w
              + v2.x*v2.x + v2.y*v2.y + v2.z*v2.z + v2.w*v2.w
              + v3.x*v3.x + v3.y*v3.y + v3.z*v3.z + v3.w*v3.w;
    ssq += __shfl_xor(ssq, 1, 64);
    ssq += __shfl_xor(ssq, 2, 64);
    float nu = fmaxf(sqrtf(ssq), 1e-15f);
    float hs = tanhf(nu) / nu;
    if (gr < NN) {
      float* op = h_out + (size_t)gr * HD + p * 16;
      *(float4*)(op + 0)  = make_float4(v0.x*hs, v0.y*hs, v0.z*hs, v0.w*hs);
      *(float4*)(op + 4)  = make_float4(v1.x*hs, v1.y*hs, v1.z*hs, v1.w*hs);
      *(float4*)(op + 8)  = make_float4(v2.x*hs, v2.y*hs, v2.z*hs, v2.w*hs);
      *(float4*)(op + 12) = make_float4(v3.x*hs, v3.y*hs, v3.z*hs, v3.w*hs);
    }
  }
}

// ---------------------------------------------------------------- edge scores (8 lanes/edge, 8 edges/wave)
__global__ void __launch_bounds__(256) k_edge(const int* __restrict__ src,
                                              const int* __restrict__ dst,
                                              const int* __restrict__ etype,
                                              const ushort* __restrict__ Asrc,
                                              const ushort* __restrict__ Adst,
                                              const ushort* __restrict__ Te2bf,
                                              const float* __restrict__ Wes2,
                                              const float* __restrict__ bes2,
                                              float* __restrict__ edge_scores) {
  int t = threadIdx.x;
  int lane = t & 63;
  int lq = lane & 7, lg = lane >> 3;
  int w = (blockIdx.x * 256 + t) >> 6;
  int e = w * 8 + lg;
  float p = 0.f;
  if (e < NE) {
    int si = src[e], di = dst[e], ti = etype[e];
    uint4 av = *(const uint4*)&Asrc[(size_t)si * HD + lq * 8];
    uint4 bv = *(const uint4*)&Adst[(size_t)di * HD + lq * 8];
    uint4 tv = *(const uint4*)&Te2bf[ti * HD + lq * 8];
    const float* wp = &Wes2[lq * 8];
    float4 w0 = *(const float4*)wp;
    float4 w1 = *(const float4*)(wp + 4);
    p += fmaxf(bflo(av.x) + bflo(bv.x) + bflo(tv.x), 0.f) * w0.x;
    p += fmaxf(bfhi(av.x) + bfhi(bv.x) + bfhi(tv.x), 0.f) * w0.y;
    p += fmaxf(bflo(av.y) + bflo(bv.y) + bflo(tv.y), 0.f) * w0.z;
    p += fmaxf(bfhi(av.y) + bfhi(bv.y) + bfhi(tv.y), 0.f) * w0.w;
    p += fmaxf(bflo(av.z) + bflo(bv.z) + bflo(tv.z), 0.f) * w1.x;
    p += fmaxf(bfhi(av.z) + bfhi(bv.z) + bfhi(tv.z), 0.f) * w1.y;
    p += fmaxf(bflo(av.w) + bflo(bv.w) + bflo(tv.w), 0.f) * w1.z;
    p += fmaxf(bfhi(av.w) + bfhi(bv.w) + bfhi(tv.w), 0.f) * w1.w;
  }
  p += __shfl_xor(p, 1, 64);
  p += __shfl_xor(p, 2, 64);
  p += __shfl_xor(p, 4, 64);
  if (e < NE && lq == 0) edge_scores[e] = 1.f / (1.f + __expf(-(p + bes2[0])));
}

// ---------------------------------------------------------------- launch
extern "C" void kernel_launch(void* const* d_in, const int* in_sizes, int n_in,
                              void* d_out, int out_size, void* d_ws, size_t ws_size,
                              hipStream_t stream) {
  const float* node_features = (const float*)d_in[0];
  const float* edge_desc = (const float*)d_in[1];
  const float* query = (const float*)d_in[2];
  const float* Wn = (const float*)d_in[3];
  const float* bn = (const float*)d_in[4];
  const float* ts = (const float*)d_in[5];
  const float* Wq = (const float*)d_in[6];
  const float* bq = (const float*)d_in[7];
  const float* Ws_ = (const float*)d_in[8];
  const float* bs = (const float*)d_in[9];
  const float* attn_a = (const float*)d_in[10];
  const float* Wmp = (const float*)d_in[11];
  const float* bmp = (const float*)d_in[12];
  const float* Wns1 = (const float*)d_in[13];
  const float* bns1 = (const float*)d_in[14];
  const float* Wns2 = (const float*)d_in[15];
  const float* bns2 = (const float*)d_in[16];
  const float* Wes1 = (const float*)d_in[17];
  const float* bes1 = (const float*)d_in[18];
  const float* Wes2 = (const float*)d_in[19];
  const float* bes2 = (const float*)d_in[20];
  const int* edge_index = (const int*)d_in[21];
  const int* etype = (const int*)d_in[22];
  const int* src = edge_index;
  const int* dst = edge_index + NE;

  float* out_ns = (float*)d_out;
  float* out_es = out_ns + NN;
  float* out_h = out_es + NE;
  float* out_te = out_h + (size_t)NN * HD;

  char* w = (char*)d_ws;
  auto alloc = [&](size_t bytes) {
    char* p = w;
    w += (bytes + 1023) & ~(size_t)1023;
    return p;
  };
  float* ht_a = (float*)alloc((size_t)NN * HD * 4);
  float* ht_b = (float*)alloc((size_t)NN * HD * 4);
  ushort* msgbf = (ushort*)alloc((size_t)NN * HD * 2);
  ushort* Asrc = (ushort*)alloc((size_t)NN * HD * 2);
  ushort* Adst = (ushort*)alloc((size_t)NN * HD * 2);
  float* p_src = (float*)alloc(NN * 4);
  float* p_dst = (float*)alloc(NN * 4);
  float* s_buf = (float*)alloc(NE * 4);
  float* qb = (float*)alloc(HD * 4);
  float* qe = (float*)alloc(HD * 4);
  float* ta3 = (float*)alloc(NLAY * NTT * 4);
  ushort* Te2bf = (ushort*)alloc(NTT * HD * 2);
  int* cnt = (int*)alloc(NN * 4);
  int* row_ptr = (int*)alloc((NN + 1) * 4);
  int* bsum = (int*)alloc(NCHUNK * 4);
  int* boff = (int*)alloc(NCHUNK * 4);
  int* bucket_cursor = (int*)alloc(NBUCK * 4);
  uint* csr = (uint*)alloc(NE * 4);
  // ebuf (NE x 4B = 3.2 MB) aliases Asrc (6.4 MB): CSR build finishes before
  // k_score writes Asrc. No overlap in stream order.
  uint* ebuf = (uint*)Asrc;

  hipMemsetAsync(cnt, 0, NN * 4, stream);
  k_setup<<<1, 256, 0, stream>>>(edge_desc, query, Wq, bq, Ws_, bs, attn_a, Wns1, bns1,
                                 Wes1, bes1, out_te, qb, ta3, qe);
  k_te2<<<16, 256, 0, stream>>>(out_te, qe, Wes1, Te2bf);
  k_hist<<<NE / 256, 256, 0, stream>>>(dst, cnt);
  k_scanA<<<NCHUNK, 256, 0, stream>>>(cnt, bsum);
  k_scanB<<<1, 64, 0, stream>>>(bsum, boff, row_ptr);
  k_scanC<<<NCHUNK, 256, 0, stream>>>(cnt, boff, row_ptr, bucket_cursor);
  k_bin<<<NBINBLK, 256, 0, stream>>>(src, dst, etype, bucket_cursor, ebuf);
  k_scatter2<<<NBUCK, 256, 0, stream>>>(row_ptr, ebuf, csr);
  // k_proj with fused layer-0 msg
  k_proj<<<(NN + 63) / 64, 256, 0, stream>>>(node_features, Wn, bn, ts, ht_a,
                                             Wmp, bmp, attn_a, msgbf, p_src, p_dst);

  float* cur = ht_a;
  float* nxt = ht_b;
  for (int l = 0; l < NLAY; ++l) {
    if (l > 0)
      k_msg<<<(NN + 63) / 64, 256, 0, stream>>>(cur, Wmp + l * HD * HD, bmp + l * HD,
                                                attn_a + l * (2 * HD + TDD), msgbf, p_src, p_dst);
    k_agg<<<(NN + 3) / 4, 256, 0, stream>>>(row_ptr, csr, p_src, p_dst, ta3 + l * NTT,
                                            msgbf, nxt, s_buf);
    float* tmp = cur; cur = nxt; nxt = tmp;
  }
  k_score<<<(NN + 63) / 64, 256, 0, stream>>>(cur, Wns1, qb, Wns2, bns2, Wes1,
                                              out_ns, out_h, Asrc, Adst);
  k_edge<<<(NE + 31) / 32, 256, 0, stream>>>(src, dst, etype, Asrc, Adst, Te2bf,
                                             Wes2, bes2, out_es);
}